// Round 1
// baseline (3901.830 us; speedup 1.0000x reference)
//
#include <hip/hip_runtime.h>
#include <hip/hip_bf16.h>

#define NN 100000   // nodes
#define NE 1600000  // edges
#define NF 512      // in features
#define NH 128      // hidden
#define NC 20       // classes

static __device__ __forceinline__ void atomAddF(float* p, float v) {
    unsafeAtomicAdd(p, v);   // emits global_atomic_add_f32 on gfx950
}

// ---------------- degree / normalization ----------------

__global__ __launch_bounds__(256) void k_deg_init(float* __restrict__ deg) {
    int i = blockIdx.x * 256 + threadIdx.x;
    if (i < NN) deg[i] = 1.0f;   // self-loop weight
}

__global__ __launch_bounds__(256) void k_deg_edges(const int* __restrict__ ei,
        const float* __restrict__ ew, float* __restrict__ deg) {
    int e = blockIdx.x * 256 + threadIdx.x;
    if (e < NE) atomAddF(&deg[ei[NE + e]], ew[e]);   // target = col
}

__global__ __launch_bounds__(256) void k_dinv(float* __restrict__ deg) {
    int i = blockIdx.x * 256 + threadIdx.x;
    if (i < NN) { float d = deg[i]; deg[i] = d > 0.f ? rsqrtf(d) : 0.f; }
}

__global__ __launch_bounds__(256) void k_coeff(const int* __restrict__ ei,
        const float* __restrict__ ew, const float* __restrict__ dinv,
        float* __restrict__ coeff) {
    int e = blockIdx.x * 256 + threadIdx.x;
    if (e < NE) coeff[e] = dinv[ei[e]] * ew[e] * dinv[ei[NE + e]];
}

// ---------------- GEMM1: h[N,128] = x[N,512] @ W1[512,128] ----------------
// 64-row tile, full 128 cols, BK=32. 256 threads, 4x8 micro-tile each.

__global__ __launch_bounds__(256) void k_gemm1(const float* __restrict__ x,
        const float* __restrict__ W1, float* __restrict__ h) {
    __shared__ float xs[64][36];     // +4 pad keeps float4 alignment, breaks bank stride
    __shared__ float ws[32][NH];
    int tid = threadIdx.x;
    int r0 = blockIdx.x * 64;
    int tr = (tid >> 4) * 4;         // 0..60
    int tc = (tid & 15) * 8;         // 0..120
    float acc[4][8] = {};

    for (int kc = 0; kc < NF; kc += 32) {
        // stage x tile: 64x32
        {
            int lr = tid >> 3;              // 0..31
            int lc = (tid & 7) * 4;         // 0..28
            #pragma unroll
            for (int i = 0; i < 64; i += 32) {
                int gr = r0 + lr + i;
                float4 v = make_float4(0.f, 0.f, 0.f, 0.f);
                if (gr < NN) v = *(const float4*)&x[(size_t)gr * NF + kc + lc];
                *(float4*)&xs[lr + i][lc] = v;
            }
        }
        // stage W1 tile: 32x128
        {
            int lr = tid >> 5;              // 0..7
            int lc = (tid & 31) * 4;        // 0..124
            #pragma unroll
            for (int i = 0; i < 4; i++) {
                int rr = lr + i * 8;
                *(float4*)&ws[rr][lc] = *(const float4*)&W1[(size_t)(kc + rr) * NH + lc];
            }
        }
        __syncthreads();
        #pragma unroll 8
        for (int k = 0; k < 32; k++) {
            float a[4], b[8];
            #pragma unroll
            for (int i = 0; i < 4; i++) a[i] = xs[tr + i][k];
            #pragma unroll
            for (int j = 0; j < 8; j++) b[j] = ws[k][tc + j];
            #pragma unroll
            for (int i = 0; i < 4; i++)
                #pragma unroll
                for (int j = 0; j < 8; j++)
                    acc[i][j] = fmaf(a[i], b[j], acc[i][j]);
        }
        __syncthreads();
    }
    #pragma unroll
    for (int i = 0; i < 4; i++) {
        int gr = r0 + tr + i;
        if (gr < NN) {
            *(float4*)&h[(size_t)gr * NH + tc]     = make_float4(acc[i][0], acc[i][1], acc[i][2], acc[i][3]);
            *(float4*)&h[(size_t)gr * NH + tc + 4] = make_float4(acc[i][4], acc[i][5], acc[i][6], acc[i][7]);
        }
    }
}

// ---------------- aggregation 1 (128-wide) ----------------

__global__ __launch_bounds__(256) void k_agg1_init(const float* __restrict__ h,
        const float* __restrict__ dinv, float* __restrict__ hagg) {
    long t = (long)blockIdx.x * 256 + threadIdx.x;
    if (t >= (long)NN * 32) return;
    int n = (int)(t >> 5);
    int j = ((int)t & 31) * 4;
    float d = dinv[n]; float s = d * d;     // self-loop norm
    float4 v = *(const float4*)&h[(size_t)n * NH + j];
    *(float4*)&hagg[(size_t)n * NH + j] = make_float4(v.x * s, v.y * s, v.z * s, v.w * s);
}

__global__ __launch_bounds__(256) void k_agg1_edges(const int* __restrict__ ei,
        const float* __restrict__ coeff, const float* __restrict__ h,
        float* __restrict__ hagg) {
    long t = (long)blockIdx.x * 256 + threadIdx.x;
    int e = (int)(t >> 5);
    if (e >= NE) return;
    int j = ((int)t & 31) * 4;
    int r = ei[e], c = ei[NE + e];
    float cf = coeff[e];
    float4 v = *(const float4*)&h[(size_t)r * NH + j];
    float* dst = &hagg[(size_t)c * NH + j];
    atomAddF(dst + 0, v.x * cf);
    atomAddF(dst + 1, v.y * cf);
    atomAddF(dst + 2, v.z * cf);
    atomAddF(dst + 3, v.w * cf);
}

__global__ __launch_bounds__(256) void k_bias_relu(float* __restrict__ hagg,
        const float* __restrict__ b1) {
    long t = (long)blockIdx.x * 256 + threadIdx.x;
    if (t >= (long)NN * 32) return;
    int n = (int)(t >> 5);
    int j = ((int)t & 31) * 4;
    float4 v = *(const float4*)&hagg[(size_t)n * NH + j];
    float4 b = *(const float4*)&b1[j];
    v.x = fmaxf(v.x + b.x, 0.f);
    v.y = fmaxf(v.y + b.y, 0.f);
    v.z = fmaxf(v.z + b.z, 0.f);
    v.w = fmaxf(v.w + b.w, 0.f);
    *(float4*)&hagg[(size_t)n * NH + j] = v;
}

// ---------------- GEMM2: h2[N,20] = hr[N,128] @ W2[128,20] ----------------

__global__ __launch_bounds__(256) void k_gemm2(const float* __restrict__ hr,
        const float* __restrict__ W2, float* __restrict__ h2) {
    __shared__ float xs[128][132];
    __shared__ float ws[128][20];
    int tid = threadIdx.x;
    int r0 = blockIdx.x * 128;
    // stage W2 (2560 floats = 640 float4)
    #pragma unroll
    for (int it = 0; it < 3; it++) {
        int idx = it * 256 + tid;
        if (idx < 640) {
            int rr = idx / 5, cg = idx % 5;
            *(float4*)&ws[rr][cg * 4] = *(const float4*)&W2[(size_t)rr * NC + cg * 4];
        }
    }
    // stage hr tile 128x128
    #pragma unroll
    for (int it = 0; it < 16; it++) {
        int rr = it * 8 + (tid >> 5);
        int cc = (tid & 31) * 4;
        int gr = r0 + rr;
        float4 v = make_float4(0.f, 0.f, 0.f, 0.f);
        if (gr < NN) v = *(const float4*)&hr[(size_t)gr * NH + cc];
        *(float4*)&xs[rr][cc] = v;
    }
    __syncthreads();
    int r  = tid >> 1;
    int c0 = (tid & 1) * 10;
    float acc[10] = {};
    for (int k = 0; k < NH; k++) {
        float a = xs[r][k];
        #pragma unroll
        for (int j = 0; j < 5; j++) {
            float2 b = *(const float2*)&ws[k][c0 + 2 * j];
            acc[2 * j]     = fmaf(a, b.x, acc[2 * j]);
            acc[2 * j + 1] = fmaf(a, b.y, acc[2 * j + 1]);
        }
    }
    int gr = r0 + r;
    if (gr < NN) {
        #pragma unroll
        for (int j = 0; j < 5; j++)
            *(float2*)&h2[(size_t)gr * NC + c0 + 2 * j] = make_float2(acc[2 * j], acc[2 * j + 1]);
    }
}

// ---------------- aggregation 2 (20-wide) ----------------

__global__ __launch_bounds__(256) void k_agg2_init(const float* __restrict__ h2,
        const float* __restrict__ dinv, float* __restrict__ out) {
    int t = blockIdx.x * 256 + threadIdx.x;
    if (t >= NN * 5) return;
    int n = t / 5, g = t % 5;
    float d = dinv[n]; float s = d * d;
    float4 v = *(const float4*)&h2[(size_t)n * NC + g * 4];
    *(float4*)&out[(size_t)n * NC + g * 4] = make_float4(v.x * s, v.y * s, v.z * s, v.w * s);
}

__global__ __launch_bounds__(256) void k_agg2_edges(const int* __restrict__ ei,
        const float* __restrict__ coeff, const float* __restrict__ h2,
        float* __restrict__ out) {
    long t = (long)blockIdx.x * 256 + threadIdx.x;
    int e = (int)(t >> 3);
    if (e >= NE) return;
    int g = (int)t & 7;
    if (g >= 5) return;
    int r = ei[e], c = ei[NE + e];
    float cf = coeff[e];
    float4 v = *(const float4*)&h2[(size_t)r * NC + g * 4];
    float* dst = &out[(size_t)c * NC + g * 4];
    atomAddF(dst + 0, v.x * cf);
    atomAddF(dst + 1, v.y * cf);
    atomAddF(dst + 2, v.z * cf);
    atomAddF(dst + 3, v.w * cf);
}

// ---------------- log_softmax (in place on d_out) ----------------

__global__ __launch_bounds__(256) void k_logsoftmax(float* __restrict__ out,
        const float* __restrict__ b2) {
    int i = blockIdx.x * 256 + threadIdx.x;
    if (i >= NN) return;
    float v[20];
    #pragma unroll
    for (int g = 0; g < 5; g++) {
        float4 t = *(const float4*)&out[(size_t)i * NC + g * 4];
        float4 b = *(const float4*)&b2[g * 4];
        v[g * 4 + 0] = t.x + b.x; v[g * 4 + 1] = t.y + b.y;
        v[g * 4 + 2] = t.z + b.z; v[g * 4 + 3] = t.w + b.w;
    }
    float m = v[0];
    #pragma unroll
    for (int j = 1; j < 20; j++) m = fmaxf(m, v[j]);
    float s = 0.f;
    #pragma unroll
    for (int j = 0; j < 20; j++) s += __expf(v[j] - m);
    float l = m + __logf(s);
    #pragma unroll
    for (int g = 0; g < 5; g++)
        *(float4*)&out[(size_t)i * NC + g * 4] =
            make_float4(v[g * 4] - l, v[g * 4 + 1] - l, v[g * 4 + 2] - l, v[g * 4 + 3] - l);
}

// ---------------- launch ----------------

extern "C" void kernel_launch(void* const* d_in, const int* in_sizes, int n_in,
                              void* d_out, int out_size, void* d_ws, size_t ws_size,
                              hipStream_t stream) {
    const float* x  = (const float*)d_in[0];
    const int*   ei = (const int*)d_in[1];
    const float* ew = (const float*)d_in[2];
    const float* W1 = (const float*)d_in[3];
    const float* b1 = (const float*)d_in[4];
    const float* W2 = (const float*)d_in[5];
    const float* b2 = (const float*)d_in[6];
    float* out = (float*)d_out;

    char* ws = (char*)d_ws;
    float* dinv  = (float*)(ws);                    // NN floats (deg -> dinv in place)
    float* coeff = (float*)(ws + (1u  << 20));      // NE floats (6.4 MB)
    float* h     = (float*)(ws + (8u  << 20));      // NN*NH floats (51.2 MB); reused as h2
    float* hagg  = (float*)(ws + (64u << 20));      // NN*NH floats (51.2 MB)
    float* h2    = h;                               // h dead after agg1

    dim3 b(256);
    k_deg_init  <<<(NN + 255) / 256, b, 0, stream>>>(dinv);
    k_deg_edges <<<(NE + 255) / 256, b, 0, stream>>>(ei, ew, dinv);
    k_dinv      <<<(NN + 255) / 256, b, 0, stream>>>(dinv);
    k_coeff     <<<(NE + 255) / 256, b, 0, stream>>>(ei, ew, dinv, coeff);

    k_gemm1     <<<(NN + 63) / 64, b, 0, stream>>>(x, W1, h);
    k_agg1_init <<<(int)(((long)NN * 32 + 255) / 256), b, 0, stream>>>(h, dinv, hagg);
    k_agg1_edges<<<(int)(((long)NE * 32 + 255) / 256), b, 0, stream>>>(ei, coeff, h, hagg);
    k_bias_relu <<<(int)(((long)NN * 32 + 255) / 256), b, 0, stream>>>(hagg, b1);

    k_gemm2     <<<(NN + 127) / 128, b, 0, stream>>>(hagg, W2, h2);
    k_agg2_init <<<(NN * 5 + 255) / 256, b, 0, stream>>>(h2, dinv, out);
    k_agg2_edges<<<(int)(((long)NE * 8 + 255) / 256), b, 0, stream>>>(ei, coeff, h2, out);
    k_logsoftmax<<<(NN + 255) / 256, b, 0, stream>>>(out, b2);
}

// Round 2
// 847.381 us; speedup vs baseline: 4.6046x; 4.6046x over previous
//
#include <hip/hip_runtime.h>
#include <hip/hip_bf16.h>

#define NN 100000   // nodes
#define NE 1600000  // edges
#define NF 512      // in features
#define NH 128      // hidden
#define NC 20       // classes

#define SCAN_NBLK 98   // ceil(NN/1024)

// ---------------- degree + in-degree count ----------------

__global__ __launch_bounds__(256) void k_init(float* __restrict__ deg, int* __restrict__ cnt) {
    int i = blockIdx.x * 256 + threadIdx.x;
    if (i < NN) { deg[i] = 1.0f; cnt[i] = 0; }   // self-loop weight 1
}

__global__ __launch_bounds__(256) void k_deg_count(const int* __restrict__ ei,
        const float* __restrict__ ew, float* __restrict__ deg, int* __restrict__ cnt) {
    int e = blockIdx.x * 256 + threadIdx.x;
    if (e < NE) {
        int c = ei[NE + e];
        unsafeAtomicAdd(&deg[c], ew[e]);
        atomicAdd(&cnt[c], 1);
    }
}

__global__ __launch_bounds__(256) void k_dinv(float* __restrict__ deg) {
    int i = blockIdx.x * 256 + threadIdx.x;
    if (i < NN) { float d = deg[i]; deg[i] = d > 0.f ? rsqrtf(d) : 0.f; }
}

// ---------------- exclusive scan of cnt -> ptr (3 kernels) ----------------

__global__ __launch_bounds__(256) void k_scan_a(const int* __restrict__ cnt, int* __restrict__ part) {
    __shared__ int s[256];
    int b = blockIdx.x, t = threadIdx.x;
    int base = b * 1024 + t * 4;
    int sum = 0;
    #pragma unroll
    for (int i = 0; i < 4; i++) { int idx = base + i; if (idx < NN) sum += cnt[idx]; }
    s[t] = sum; __syncthreads();
    for (int o = 128; o; o >>= 1) { if (t < o) s[t] += s[t + o]; __syncthreads(); }
    if (t == 0) part[b] = s[0];
}

__global__ void k_scan_b(int* __restrict__ part) {
    if (threadIdx.x == 0 && blockIdx.x == 0) {
        int acc = 0;
        for (int i = 0; i < SCAN_NBLK; i++) { int v = part[i]; part[i] = acc; acc += v; }
    }
}

__global__ __launch_bounds__(256) void k_scan_c(const int* __restrict__ cnt,
        const int* __restrict__ part, int* __restrict__ ptr, int* __restrict__ cursor) {
    __shared__ int s[256];
    int b = blockIdx.x, t = threadIdx.x;
    int base = b * 1024 + t * 4;
    int v[4]; int sum = 0;
    #pragma unroll
    for (int i = 0; i < 4; i++) { int idx = base + i; v[i] = (idx < NN) ? cnt[idx] : 0; sum += v[i]; }
    s[t] = sum; __syncthreads();
    // Hillis-Steele inclusive scan
    for (int o = 1; o < 256; o <<= 1) {
        int x = (t >= o) ? s[t - o] : 0;
        __syncthreads();
        s[t] += x;
        __syncthreads();
    }
    int off = part[b] + s[t] - sum;   // exclusive offset for this thread's 4 elems
    #pragma unroll
    for (int i = 0; i < 4; i++) {
        int idx = base + i;
        if (idx < NN) { ptr[idx] = off; cursor[idx] = off; off += v[i]; }
    }
    if (b == 0 && t == 0) ptr[NN] = NE;
}

// ---------------- CSR scatter (int atomics only) ----------------

__global__ __launch_bounds__(256) void k_scatter(const int* __restrict__ ei,
        const float* __restrict__ ew, const float* __restrict__ dinv,
        int* __restrict__ cursor, int2* __restrict__ csre) {
    int e = blockIdx.x * 256 + threadIdx.x;
    if (e >= NE) return;
    int r = ei[e], c = ei[NE + e];
    float cf = dinv[r] * ew[e] * dinv[c];
    int pos = atomicAdd(&cursor[c], 1);
    csre[pos] = make_int2(r, __float_as_int(cf));
}

// ---------------- GEMM1: h[N,128] = x[N,512] @ W1[512,128] ----------------

__global__ __launch_bounds__(256) void k_gemm1(const float* __restrict__ x,
        const float* __restrict__ W1, float* __restrict__ h) {
    __shared__ float xs[64][36];
    __shared__ float ws[32][NH];
    int tid = threadIdx.x;
    int r0 = blockIdx.x * 64;
    int tr = (tid >> 4) * 4;
    int tc = (tid & 15) * 8;
    float acc[4][8] = {};

    for (int kc = 0; kc < NF; kc += 32) {
        {
            int lr = tid >> 3;
            int lc = (tid & 7) * 4;
            #pragma unroll
            for (int i = 0; i < 64; i += 32) {
                int gr = r0 + lr + i;
                float4 v = make_float4(0.f, 0.f, 0.f, 0.f);
                if (gr < NN) v = *(const float4*)&x[(size_t)gr * NF + kc + lc];
                *(float4*)&xs[lr + i][lc] = v;
            }
        }
        {
            int lr = tid >> 5;
            int lc = (tid & 31) * 4;
            #pragma unroll
            for (int i = 0; i < 4; i++) {
                int rr = lr + i * 8;
                *(float4*)&ws[rr][lc] = *(const float4*)&W1[(size_t)(kc + rr) * NH + lc];
            }
        }
        __syncthreads();
        #pragma unroll 8
        for (int k = 0; k < 32; k++) {
            float a[4], b[8];
            #pragma unroll
            for (int i = 0; i < 4; i++) a[i] = xs[tr + i][k];
            #pragma unroll
            for (int j = 0; j < 8; j++) b[j] = ws[k][tc + j];
            #pragma unroll
            for (int i = 0; i < 4; i++)
                #pragma unroll
                for (int j = 0; j < 8; j++)
                    acc[i][j] = fmaf(a[i], b[j], acc[i][j]);
        }
        __syncthreads();
    }
    #pragma unroll
    for (int i = 0; i < 4; i++) {
        int gr = r0 + tr + i;
        if (gr < NN) {
            *(float4*)&h[(size_t)gr * NH + tc]     = make_float4(acc[i][0], acc[i][1], acc[i][2], acc[i][3]);
            *(float4*)&h[(size_t)gr * NH + tc + 4] = make_float4(acc[i][4], acc[i][5], acc[i][6], acc[i][7]);
        }
    }
}

// ---------------- aggregation 1: CSR gather, fused self-loop+bias+relu ----------
// 32 lanes per node; lane j owns features [4j, 4j+4).

__global__ __launch_bounds__(256) void k_agg1_gather(const float* __restrict__ h,
        const float* __restrict__ dinv, const int* __restrict__ ptr,
        const int2* __restrict__ csre, const float* __restrict__ b1,
        float* __restrict__ hagg) {
    int tid = blockIdx.x * 256 + threadIdx.x;
    int n = tid >> 5;
    if (n >= NN) return;
    int j = (tid & 31) * 4;
    float d = dinv[n]; float s = d * d;
    float4 v = *(const float4*)&h[(size_t)n * NH + j];
    float4 acc = make_float4(v.x * s, v.y * s, v.z * s, v.w * s);
    int p0 = ptr[n], p1 = ptr[n + 1];
    for (int p = p0; p < p1; p++) {
        int2 e = csre[p];
        float cf = __int_as_float(e.y);
        float4 u = *(const float4*)&h[(size_t)e.x * NH + j];
        acc.x = fmaf(cf, u.x, acc.x);
        acc.y = fmaf(cf, u.y, acc.y);
        acc.z = fmaf(cf, u.z, acc.z);
        acc.w = fmaf(cf, u.w, acc.w);
    }
    float4 b = *(const float4*)&b1[j];
    acc.x = fmaxf(acc.x + b.x, 0.f);
    acc.y = fmaxf(acc.y + b.y, 0.f);
    acc.z = fmaxf(acc.z + b.z, 0.f);
    acc.w = fmaxf(acc.w + b.w, 0.f);
    *(float4*)&hagg[(size_t)n * NH + j] = acc;
}

// ---------------- GEMM2: h2[N,20] = hagg[N,128] @ W2[128,20] ----------------

__global__ __launch_bounds__(256) void k_gemm2(const float* __restrict__ hr,
        const float* __restrict__ W2, float* __restrict__ h2) {
    __shared__ float xs[128][132];
    __shared__ float ws[128][20];
    int tid = threadIdx.x;
    int r0 = blockIdx.x * 128;
    #pragma unroll
    for (int it = 0; it < 3; it++) {
        int idx = it * 256 + tid;
        if (idx < 640) {
            int rr = idx / 5, cg = idx % 5;
            *(float4*)&ws[rr][cg * 4] = *(const float4*)&W2[(size_t)rr * NC + cg * 4];
        }
    }
    #pragma unroll
    for (int it = 0; it < 16; it++) {
        int rr = it * 8 + (tid >> 5);
        int cc = (tid & 31) * 4;
        int gr = r0 + rr;
        float4 v = make_float4(0.f, 0.f, 0.f, 0.f);
        if (gr < NN) v = *(const float4*)&hr[(size_t)gr * NH + cc];
        *(float4*)&xs[rr][cc] = v;
    }
    __syncthreads();
    int r  = tid >> 1;
    int c0 = (tid & 1) * 10;
    float acc[10] = {};
    for (int k = 0; k < NH; k++) {
        float a = xs[r][k];
        #pragma unroll
        for (int j = 0; j < 5; j++) {
            float2 b = *(const float2*)&ws[k][c0 + 2 * j];
            acc[2 * j]     = fmaf(a, b.x, acc[2 * j]);
            acc[2 * j + 1] = fmaf(a, b.y, acc[2 * j + 1]);
        }
    }
    int gr = r0 + r;
    if (gr < NN) {
        #pragma unroll
        for (int j = 0; j < 5; j++)
            *(float2*)&h2[(size_t)gr * NC + c0 + 2 * j] = make_float2(acc[2 * j], acc[2 * j + 1]);
    }
}

// ---------------- aggregation 2 + bias + log_softmax, fully fused -----------
// one thread per node, 20 accumulators in registers.

__global__ __launch_bounds__(256) void k_agg2_fused(const float* __restrict__ h2,
        const float* __restrict__ dinv, const int* __restrict__ ptr,
        const int2* __restrict__ csre, const float* __restrict__ b2,
        float* __restrict__ out) {
    int n = blockIdx.x * 256 + threadIdx.x;
    if (n >= NN) return;
    float acc[20];
    float d = dinv[n]; float s = d * d;
    #pragma unroll
    for (int g = 0; g < 5; g++) {
        float4 v = *(const float4*)&h2[(size_t)n * NC + g * 4];
        acc[g * 4 + 0] = v.x * s; acc[g * 4 + 1] = v.y * s;
        acc[g * 4 + 2] = v.z * s; acc[g * 4 + 3] = v.w * s;
    }
    int p0 = ptr[n], p1 = ptr[n + 1];
    for (int p = p0; p < p1; p++) {
        int2 e = csre[p];
        float cf = __int_as_float(e.y);
        const float* hr = &h2[(size_t)e.x * NC];
        #pragma unroll
        for (int g = 0; g < 5; g++) {
            float4 v = *(const float4*)&hr[g * 4];
            acc[g * 4 + 0] = fmaf(cf, v.x, acc[g * 4 + 0]);
            acc[g * 4 + 1] = fmaf(cf, v.y, acc[g * 4 + 1]);
            acc[g * 4 + 2] = fmaf(cf, v.z, acc[g * 4 + 2]);
            acc[g * 4 + 3] = fmaf(cf, v.w, acc[g * 4 + 3]);
        }
    }
    #pragma unroll
    for (int j = 0; j < 20; j++) acc[j] += b2[j];
    float m = acc[0];
    #pragma unroll
    for (int j = 1; j < 20; j++) m = fmaxf(m, acc[j]);
    float ssum = 0.f;
    #pragma unroll
    for (int j = 0; j < 20; j++) ssum += __expf(acc[j] - m);
    float l = m + __logf(ssum);
    #pragma unroll
    for (int g = 0; g < 5; g++)
        *(float4*)&out[(size_t)n * NC + g * 4] =
            make_float4(acc[g * 4] - l, acc[g * 4 + 1] - l, acc[g * 4 + 2] - l, acc[g * 4 + 3] - l);
}

// ---------------- launch ----------------

extern "C" void kernel_launch(void* const* d_in, const int* in_sizes, int n_in,
                              void* d_out, int out_size, void* d_ws, size_t ws_size,
                              hipStream_t stream) {
    const float* x  = (const float*)d_in[0];
    const int*   ei = (const int*)d_in[1];
    const float* ew = (const float*)d_in[2];
    const float* W1 = (const float*)d_in[3];
    const float* b1 = (const float*)d_in[4];
    const float* W2 = (const float*)d_in[5];
    const float* b2 = (const float*)d_in[6];
    float* out = (float*)d_out;

    char* ws = (char*)d_ws;
    float* dinv  = (float*)(ws + 0);          // NN f32 (deg -> dinv in place)
    int*   cnt   = (int*)  (ws + 409600);     // NN i32
    int*   ptr   = (int*)  (ws + 819200);     // NN+1 i32
    int*   cursor= (int*)  (ws + 1228800);    // NN i32
    int*   part  = (int*)  (ws + 1638400);    // SCAN_NBLK i32
    int2*  csre  = (int2*) (ws + 1703936);    // NE int2 {src, coeff} (12.8 MB)
    float* h     = (float*)(ws + 14680064);   // NN*NH f32 (51.2 MB); reused as h2
    float* hagg  = (float*)(ws + 66060288);   // NN*NH f32 (51.2 MB)
    float* h2    = h;                         // h dead after agg1 gather

    dim3 b(256);
    k_init      <<<(NN + 255) / 256, b, 0, stream>>>(dinv, cnt);
    k_deg_count <<<(NE + 255) / 256, b, 0, stream>>>(ei, ew, dinv, cnt);
    k_dinv      <<<(NN + 255) / 256, b, 0, stream>>>(dinv);
    k_scan_a    <<<SCAN_NBLK, b, 0, stream>>>(cnt, part);
    k_scan_b    <<<1, 64, 0, stream>>>(part);
    k_scan_c    <<<SCAN_NBLK, b, 0, stream>>>(cnt, part, ptr, cursor);
    k_scatter   <<<(NE + 255) / 256, b, 0, stream>>>(ei, ew, dinv, cursor, csre);

    k_gemm1     <<<(NN + 63) / 64, b, 0, stream>>>(x, W1, h);
    k_agg1_gather<<<(int)(((long)NN * 32 + 255) / 256), b, 0, stream>>>(h, dinv, ptr, csre, b1, hagg);
    k_gemm2     <<<(NN + 127) / 128, b, 0, stream>>>(hagg, W2, h2);
    k_agg2_fused<<<(NN + 255) / 256, b, 0, stream>>>(h2, dinv, ptr, csre, b2, out);
}

// Round 3
// 797.262 us; speedup vs baseline: 4.8940x; 1.0629x over previous
//
#include <hip/hip_runtime.h>
#include <hip/hip_bf16.h>

#define NN 100000   // nodes
#define NE 1600000  // edges
#define NF 512      // in features
#define NH 128      // hidden
#define NC 20       // classes

#define SCAN_NBLK 98   // ceil(NN/1024)

typedef __attribute__((ext_vector_type(8))) short short8;
typedef __attribute__((ext_vector_type(4))) float f32x4;

static __device__ __forceinline__ unsigned short f2b(float x) {  // f32 -> bf16 RNE
    unsigned u = __float_as_uint(x);
    u += 0x7fffu + ((u >> 16) & 1u);
    return (unsigned short)(u >> 16);
}
static __device__ __forceinline__ float b2f(unsigned short b) {
    return __uint_as_float((unsigned)b << 16);
}

// ---------------- degree + in-degree count ----------------

__global__ __launch_bounds__(256) void k_init(float* __restrict__ deg, int* __restrict__ cnt) {
    int i = blockIdx.x * 256 + threadIdx.x;
    if (i < NN) { deg[i] = 1.0f; cnt[i] = 0; }   // self-loop weight 1
}

__global__ __launch_bounds__(256) void k_deg_count(const int* __restrict__ ei,
        const float* __restrict__ ew, float* __restrict__ deg, int* __restrict__ cnt) {
    int e = blockIdx.x * 256 + threadIdx.x;
    if (e < NE) {
        int c = ei[NE + e];
        unsafeAtomicAdd(&deg[c], ew[e]);
        atomicAdd(&cnt[c], 1);
    }
}

__global__ __launch_bounds__(256) void k_dinv(float* __restrict__ deg) {
    int i = blockIdx.x * 256 + threadIdx.x;
    if (i < NN) { float d = deg[i]; deg[i] = d > 0.f ? rsqrtf(d) : 0.f; }
}

// ---------------- exclusive scan of cnt -> ptr ----------------

__global__ __launch_bounds__(256) void k_scan_a(const int* __restrict__ cnt, int* __restrict__ part) {
    __shared__ int s[256];
    int b = blockIdx.x, t = threadIdx.x;
    int base = b * 1024 + t * 4;
    int sum = 0;
    #pragma unroll
    for (int i = 0; i < 4; i++) { int idx = base + i; if (idx < NN) sum += cnt[idx]; }
    s[t] = sum; __syncthreads();
    for (int o = 128; o; o >>= 1) { if (t < o) s[t] += s[t + o]; __syncthreads(); }
    if (t == 0) part[b] = s[0];
}

__global__ void k_scan_b(int* __restrict__ part) {
    if (threadIdx.x == 0 && blockIdx.x == 0) {
        int acc = 0;
        for (int i = 0; i < SCAN_NBLK; i++) { int v = part[i]; part[i] = acc; acc += v; }
    }
}

__global__ __launch_bounds__(256) void k_scan_c(const int* __restrict__ cnt,
        const int* __restrict__ part, int* __restrict__ ptr, int* __restrict__ cursor) {
    __shared__ int s[256];
    int b = blockIdx.x, t = threadIdx.x;
    int base = b * 1024 + t * 4;
    int v[4]; int sum = 0;
    #pragma unroll
    for (int i = 0; i < 4; i++) { int idx = base + i; v[i] = (idx < NN) ? cnt[idx] : 0; sum += v[i]; }
    s[t] = sum; __syncthreads();
    for (int o = 1; o < 256; o <<= 1) {
        int x = (t >= o) ? s[t - o] : 0;
        __syncthreads();
        s[t] += x;
        __syncthreads();
    }
    int off = part[b] + s[t] - sum;
    #pragma unroll
    for (int i = 0; i < 4; i++) {
        int idx = base + i;
        if (idx < NN) { ptr[idx] = off; cursor[idx] = off; off += v[i]; }
    }
    if (b == 0 && t == 0) ptr[NN] = NE;
}

// ---------------- CSR scatter (int atomics only) ----------------

__global__ __launch_bounds__(256) void k_scatter(const int* __restrict__ ei,
        const float* __restrict__ ew, const float* __restrict__ dinv,
        int* __restrict__ cursor, int2* __restrict__ csre) {
    int e = blockIdx.x * 256 + threadIdx.x;
    if (e >= NE) return;
    int r = ei[e], c = ei[NE + e];
    float cf = dinv[r] * ew[e] * dinv[c];
    int pos = atomicAdd(&cursor[c], 1);
    csre[pos] = make_int2(r, __float_as_int(cf));
}

// ---------------- W1 split+transpose: Wt_h/Wt_l[128][512] bf16 ----------------

__global__ __launch_bounds__(256) void k_splitW(const float* __restrict__ W1,
        unsigned short* __restrict__ Wth, unsigned short* __restrict__ Wtl) {
    int idx = blockIdx.x * 256 + threadIdx.x;   // 65536 total
    int c = idx >> 9, k = idx & 511;
    float v = W1[(size_t)k * NH + c];
    unsigned short hi = f2b(v);
    Wth[(size_t)c * NF + k] = hi;
    Wtl[(size_t)c * NF + k] = f2b(v - b2f(hi));
}

// ---------------- GEMM1 via MFMA split-bf16 ----------------
// h[N,128] = x[N,512] @ W1[512,128];  C-tile 128x128 per block, 4 waves 2x2,
// 64x64 per wave, BK=64, 3 products (xh*wh + xh*wl + xl*wh).

__global__ __launch_bounds__(256) void k_gemm1(const float* __restrict__ x,
        const unsigned short* __restrict__ Wth, const unsigned short* __restrict__ Wtl,
        float* __restrict__ h) {
    __shared__ __align__(16) char smem[65536];
    char* Ah = smem;            // [128][64] bf16, swizzled
    char* Al = smem + 16384;
    char* Bh = smem + 32768;    // [128 cols][64 k] bf16, swizzled
    char* Bl = smem + 49152;

    const int tid = threadIdx.x;
    const int r0 = blockIdx.x * 128;
    const int lane = tid & 63, wid = tid >> 6;
    const int wm = wid >> 1, wn = wid & 1;
    const int l15 = lane & 15, lg = lane >> 4;
    const int srow = tid >> 4;      // 0..15 (staging)
    const int scg  = tid & 15;      // 0..15 (x4 elems)

    f32x4 acc[4][4];
    const f32x4 z = {0.f, 0.f, 0.f, 0.f};
    #pragma unroll
    for (int m = 0; m < 4; m++)
        #pragma unroll
        for (int n = 0; n < 4; n++) acc[m][n] = z;

    for (int kc = 0; kc < NF; kc += 64) {
        // ---- stage A (x rows, f32 -> bf16 hi/lo) and B (pre-split W) ----
        #pragma unroll
        for (int i = 0; i < 8; i++) {
            int row = i * 16 + srow;            // 0..127
            int boff = (row * 128 + scg * 8) ^ ((row & 7) << 4);
            int gr = r0 + row;
            float4 v = make_float4(0.f, 0.f, 0.f, 0.f);
            if (gr < NN) v = *(const float4*)&x[(size_t)gr * NF + kc + scg * 4];
            ushort4 hi, lo;
            hi.x = f2b(v.x); lo.x = f2b(v.x - b2f(hi.x));
            hi.y = f2b(v.y); lo.y = f2b(v.y - b2f(hi.y));
            hi.z = f2b(v.z); lo.z = f2b(v.z - b2f(hi.z));
            hi.w = f2b(v.w); lo.w = f2b(v.w - b2f(hi.w));
            *(ushort4*)(Ah + boff) = hi;
            *(ushort4*)(Al + boff) = lo;
            // B: row = output col c, k = kc + scg*4
            ushort4 wh = *(const ushort4*)&Wth[(size_t)row * NF + kc + scg * 4];
            ushort4 wl = *(const ushort4*)&Wtl[(size_t)row * NF + kc + scg * 4];
            *(ushort4*)(Bh + boff) = wh;
            *(ushort4*)(Bl + boff) = wl;
        }
        __syncthreads();

        #pragma unroll
        for (int kk = 0; kk < 2; kk++) {
            short8 ah[4], al[4], bh[4], bl[4];
            #pragma unroll
            for (int m = 0; m < 4; m++) {
                int ar = wm * 64 + m * 16 + l15;
                int ab = (ar * 128 + kk * 64 + lg * 16) ^ ((ar & 7) << 4);
                ah[m] = *(const short8*)(Ah + ab);
                al[m] = *(const short8*)(Al + ab);
            }
            #pragma unroll
            for (int n = 0; n < 4; n++) {
                int br = wn * 64 + n * 16 + l15;
                int bb = (br * 128 + kk * 64 + lg * 16) ^ ((br & 7) << 4);
                bh[n] = *(const short8*)(Bh + bb);
                bl[n] = *(const short8*)(Bl + bb);
            }
            #pragma unroll
            for (int m = 0; m < 4; m++)
                #pragma unroll
                for (int n = 0; n < 4; n++) {
                    acc[m][n] = __builtin_amdgcn_mfma_f32_16x16x32_bf16(ah[m], bh[n], acc[m][n], 0, 0, 0);
                    acc[m][n] = __builtin_amdgcn_mfma_f32_16x16x32_bf16(ah[m], bl[n], acc[m][n], 0, 0, 0);
                    acc[m][n] = __builtin_amdgcn_mfma_f32_16x16x32_bf16(al[m], bh[n], acc[m][n], 0, 0, 0);
                }
        }
        __syncthreads();
    }

    // ---- store: C/D layout col=lane&15, row=(lane>>4)*4+j ----
    #pragma unroll
    for (int m = 0; m < 4; m++) {
        int grb = r0 + wm * 64 + m * 16 + lg * 4;
        #pragma unroll
        for (int n = 0; n < 4; n++) {
            int gc = wn * 64 + n * 16 + l15;
            #pragma unroll
            for (int j = 0; j < 4; j++) {
                int gr = grb + j;
                if (gr < NN) h[(size_t)gr * NH + gc] = acc[m][n][j];
            }
        }
    }
}

// ---------------- aggregation 1: CSR gather, fused self-loop+bias+relu ----------

__global__ __launch_bounds__(256) void k_agg1_gather(const float* __restrict__ h,
        const float* __restrict__ dinv, const int* __restrict__ ptr,
        const int2* __restrict__ csre, const float* __restrict__ b1,
        float* __restrict__ hagg) {
    int tid = blockIdx.x * 256 + threadIdx.x;
    int n = tid >> 5;
    if (n >= NN) return;
    int j = (tid & 31) * 4;
    float d = dinv[n]; float s = d * d;
    float4 v = *(const float4*)&h[(size_t)n * NH + j];
    float4 acc = make_float4(v.x * s, v.y * s, v.z * s, v.w * s);
    int p0 = ptr[n], p1 = ptr[n + 1];
    for (int p = p0; p < p1; p++) {
        int2 e = csre[p];
        float cf = __int_as_float(e.y);
        float4 u = *(const float4*)&h[(size_t)e.x * NH + j];
        acc.x = fmaf(cf, u.x, acc.x);
        acc.y = fmaf(cf, u.y, acc.y);
        acc.z = fmaf(cf, u.z, acc.z);
        acc.w = fmaf(cf, u.w, acc.w);
    }
    float4 b = *(const float4*)&b1[j];
    acc.x = fmaxf(acc.x + b.x, 0.f);
    acc.y = fmaxf(acc.y + b.y, 0.f);
    acc.z = fmaxf(acc.z + b.z, 0.f);
    acc.w = fmaxf(acc.w + b.w, 0.f);
    *(float4*)&hagg[(size_t)n * NH + j] = acc;
}

// ---------------- GEMM2: h2[N,20] = hagg[N,128] @ W2[128,20] ----------------

__global__ __launch_bounds__(256) void k_gemm2(const float* __restrict__ hr,
        const float* __restrict__ W2, float* __restrict__ h2) {
    __shared__ float xs[128][132];
    __shared__ float ws[128][20];
    int tid = threadIdx.x;
    int r0 = blockIdx.x * 128;
    #pragma unroll
    for (int it = 0; it < 3; it++) {
        int idx = it * 256 + tid;
        if (idx < 640) {
            int rr = idx / 5, cg = idx % 5;
            *(float4*)&ws[rr][cg * 4] = *(const float4*)&W2[(size_t)rr * NC + cg * 4];
        }
    }
    #pragma unroll
    for (int it = 0; it < 16; it++) {
        int rr = it * 8 + (tid >> 5);
        int cc = (tid & 31) * 4;
        int gr = r0 + rr;
        float4 v = make_float4(0.f, 0.f, 0.f, 0.f);
        if (gr < NN) v = *(const float4*)&hr[(size_t)gr * NH + cc];
        *(float4*)&xs[rr][cc] = v;
    }
    __syncthreads();
    int r  = tid >> 1;
    int c0 = (tid & 1) * 10;
    float acc[10] = {};
    for (int k = 0; k < NH; k++) {
        float a = xs[r][k];
        #pragma unroll
        for (int j = 0; j < 5; j++) {
            float2 b = *(const float2*)&ws[k][c0 + 2 * j];
            acc[2 * j]     = fmaf(a, b.x, acc[2 * j]);
            acc[2 * j + 1] = fmaf(a, b.y, acc[2 * j + 1]);
        }
    }
    int gr = r0 + r;
    if (gr < NN) {
        #pragma unroll
        for (int j = 0; j < 5; j++)
            *(float2*)&h2[(size_t)gr * NC + c0 + 2 * j] = make_float2(acc[2 * j], acc[2 * j + 1]);
    }
}

// ---------------- aggregation 2 + bias + log_softmax, fully fused -----------

__global__ __launch_bounds__(256) void k_agg2_fused(const float* __restrict__ h2,
        const float* __restrict__ dinv, const int* __restrict__ ptr,
        const int2* __restrict__ csre, const float* __restrict__ b2,
        float* __restrict__ out) {
    int n = blockIdx.x * 256 + threadIdx.x;
    if (n >= NN) return;
    float acc[20];
    float d = dinv[n]; float s = d * d;
    #pragma unroll
    for (int g = 0; g < 5; g++) {
        float4 v = *(const float4*)&h2[(size_t)n * NC + g * 4];
        acc[g * 4 + 0] = v.x * s; acc[g * 4 + 1] = v.y * s;
        acc[g * 4 + 2] = v.z * s; acc[g * 4 + 3] = v.w * s;
    }
    int p0 = ptr[n], p1 = ptr[n + 1];
    for (int p = p0; p < p1; p++) {
        int2 e = csre[p];
        float cf = __int_as_float(e.y);
        const float* hr = &h2[(size_t)e.x * NC];
        #pragma unroll
        for (int g = 0; g < 5; g++) {
            float4 v = *(const float4*)&hr[g * 4];
            acc[g * 4 + 0] = fmaf(cf, v.x, acc[g * 4 + 0]);
            acc[g * 4 + 1] = fmaf(cf, v.y, acc[g * 4 + 1]);
            acc[g * 4 + 2] = fmaf(cf, v.z, acc[g * 4 + 2]);
            acc[g * 4 + 3] = fmaf(cf, v.w, acc[g * 4 + 3]);
        }
    }
    #pragma unroll
    for (int j = 0; j < 20; j++) acc[j] += b2[j];
    float m = acc[0];
    #pragma unroll
    for (int j = 1; j < 20; j++) m = fmaxf(m, acc[j]);
    float ssum = 0.f;
    #pragma unroll
    for (int j = 0; j < 20; j++) ssum += __expf(acc[j] - m);
    float l = m + __logf(ssum);
    #pragma unroll
    for (int g = 0; g < 5; g++)
        *(float4*)&out[(size_t)n * NC + g * 4] =
            make_float4(acc[g * 4] - l, acc[g * 4 + 1] - l, acc[g * 4 + 2] - l, acc[g * 4 + 3] - l);
}

// ---------------- launch ----------------

extern "C" void kernel_launch(void* const* d_in, const int* in_sizes, int n_in,
                              void* d_out, int out_size, void* d_ws, size_t ws_size,
                              hipStream_t stream) {
    const float* x  = (const float*)d_in[0];
    const int*   ei = (const int*)d_in[1];
    const float* ew = (const float*)d_in[2];
    const float* W1 = (const float*)d_in[3];
    const float* b1 = (const float*)d_in[4];
    const float* W2 = (const float*)d_in[5];
    const float* b2 = (const float*)d_in[6];
    float* out = (float*)d_out;

    char* ws = (char*)d_ws;
    float* dinv  = (float*)(ws + 0);          // NN f32
    int*   cnt   = (int*)  (ws + 409600);     // NN i32
    int*   ptr   = (int*)  (ws + 819200);     // NN+1 i32
    int*   cursor= (int*)  (ws + 1228800);    // NN i32
    int*   part  = (int*)  (ws + 1638400);    // SCAN_NBLK i32
    int2*  csre  = (int2*) (ws + 1703936);    // NE int2 (12.8 MB)
    float* h     = (float*)(ws + 14680064);   // NN*NH f32 (51.2 MB); reused as h2
    float* hagg  = (float*)(ws + 66060288);   // NN*NH f32 (51.2 MB)
    float* h2    = h;
    // W1 split lives at the head of hagg's region: dead once k_agg1_gather
    // starts writing hagg (gemm1 completed by then; same-stream ordering).
    unsigned short* Wth = (unsigned short*)(ws + 66060288);            // 128 KB
    unsigned short* Wtl = (unsigned short*)(ws + 66060288 + 131072);   // 128 KB

    dim3 b(256);
    k_init      <<<(NN + 255) / 256, b, 0, stream>>>(dinv, cnt);
    k_deg_count <<<(NE + 255) / 256, b, 0, stream>>>(ei, ew, dinv, cnt);
    k_dinv      <<<(NN + 255) / 256, b, 0, stream>>>(dinv);
    k_scan_a    <<<SCAN_NBLK, b, 0, stream>>>(cnt, part);
    k_scan_b    <<<1, 64, 0, stream>>>(part);
    k_scan_c    <<<SCAN_NBLK, b, 0, stream>>>(cnt, part, ptr, cursor);
    k_scatter   <<<(NE + 255) / 256, b, 0, stream>>>(ei, ew, dinv, cursor, csre);

    k_splitW    <<<256, b, 0, stream>>>(W1, Wth, Wtl);
    k_gemm1     <<<(NN + 127) / 128, b, 0, stream>>>(x, Wth, Wtl, h);
    k_agg1_gather<<<(int)(((long)NN * 32 + 255) / 256), b, 0, stream>>>(h, dinv, ptr, csre, b1, hagg);
    k_gemm2     <<<(NN + 127) / 128, b, 0, stream>>>(hagg, W2, h2);
    k_agg2_fused<<<(NN + 255) / 256, b, 0, stream>>>(h2, dinv, ptr, csre, b2, out);
}

// Round 4
// 786.866 us; speedup vs baseline: 4.9587x; 1.0132x over previous
//
#include <hip/hip_runtime.h>
#include <hip/hip_bf16.h>

#define NN 100000   // nodes
#define NE 1600000  // edges
#define NF 512      // in features
#define NH 128      // hidden
#define NC 20       // classes

#define SCAN_NBLK 98   // ceil(NN/1024)
#define BK 32
#define RS 80          // LDS row stride in bytes (64B data + 16B pad -> 2-way banks, free)

typedef __attribute__((ext_vector_type(8))) short short8;
typedef __attribute__((ext_vector_type(8))) unsigned short ushort8;
typedef __attribute__((ext_vector_type(4))) float f32x4;

static __device__ __forceinline__ unsigned short f2b(float x) {  // f32 -> bf16 RNE
    unsigned u = __float_as_uint(x);
    u += 0x7fffu + ((u >> 16) & 1u);
    return (unsigned short)(u >> 16);
}
static __device__ __forceinline__ float b2f(unsigned short b) {
    return __uint_as_float((unsigned)b << 16);
}

// ---------------- degree + in-degree count ----------------

__global__ __launch_bounds__(256) void k_init(float* __restrict__ deg, int* __restrict__ cnt) {
    int i = blockIdx.x * 256 + threadIdx.x;
    if (i < NN) { deg[i] = 1.0f; cnt[i] = 0; }   // self-loop weight 1
}

__global__ __launch_bounds__(256) void k_deg_count(const int* __restrict__ ei,
        const float* __restrict__ ew, float* __restrict__ deg, int* __restrict__ cnt) {
    int e = blockIdx.x * 256 + threadIdx.x;
    if (e < NE) {
        int c = ei[NE + e];
        unsafeAtomicAdd(&deg[c], ew[e]);
        atomicAdd(&cnt[c], 1);
    }
}

__global__ __launch_bounds__(256) void k_dinv(float* __restrict__ deg) {
    int i = blockIdx.x * 256 + threadIdx.x;
    if (i < NN) { float d = deg[i]; deg[i] = d > 0.f ? rsqrtf(d) : 0.f; }
}

// ---------------- exclusive scan of cnt -> ptr ----------------

__global__ __launch_bounds__(256) void k_scan_a(const int* __restrict__ cnt, int* __restrict__ part) {
    __shared__ int s[256];
    int b = blockIdx.x, t = threadIdx.x;
    int base = b * 1024 + t * 4;
    int sum = 0;
    #pragma unroll
    for (int i = 0; i < 4; i++) { int idx = base + i; if (idx < NN) sum += cnt[idx]; }
    s[t] = sum; __syncthreads();
    for (int o = 128; o; o >>= 1) { if (t < o) s[t] += s[t + o]; __syncthreads(); }
    if (t == 0) part[b] = s[0];
}

__global__ void k_scan_b(int* __restrict__ part) {
    if (threadIdx.x == 0 && blockIdx.x == 0) {
        int acc = 0;
        for (int i = 0; i < SCAN_NBLK; i++) { int v = part[i]; part[i] = acc; acc += v; }
    }
}

__global__ __launch_bounds__(256) void k_scan_c(const int* __restrict__ cnt,
        const int* __restrict__ part, int* __restrict__ ptr, int* __restrict__ cursor) {
    __shared__ int s[256];
    int b = blockIdx.x, t = threadIdx.x;
    int base = b * 1024 + t * 4;
    int v[4]; int sum = 0;
    #pragma unroll
    for (int i = 0; i < 4; i++) { int idx = base + i; v[i] = (idx < NN) ? cnt[idx] : 0; sum += v[i]; }
    s[t] = sum; __syncthreads();
    for (int o = 1; o < 256; o <<= 1) {
        int x = (t >= o) ? s[t - o] : 0;
        __syncthreads();
        s[t] += x;
        __syncthreads();
    }
    int off = part[b] + s[t] - sum;
    #pragma unroll
    for (int i = 0; i < 4; i++) {
        int idx = base + i;
        if (idx < NN) { ptr[idx] = off; cursor[idx] = off; off += v[i]; }
    }
    if (b == 0 && t == 0) ptr[NN] = NE;
}

// ---------------- CSR scatter (int atomics only) ----------------

__global__ __launch_bounds__(256) void k_scatter(const int* __restrict__ ei,
        const float* __restrict__ ew, const float* __restrict__ dinv,
        int* __restrict__ cursor, int2* __restrict__ csre) {
    int e = blockIdx.x * 256 + threadIdx.x;
    if (e >= NE) return;
    int r = ei[e], c = ei[NE + e];
    float cf = dinv[r] * ew[e] * dinv[c];
    int pos = atomicAdd(&cursor[c], 1);
    csre[pos] = make_int2(r, __float_as_int(cf));
}

// ---------------- W1 split+transpose: Wt_h/Wt_l[128][512] bf16 ----------------

__global__ __launch_bounds__(256) void k_splitW(const float* __restrict__ W1,
        unsigned short* __restrict__ Wth, unsigned short* __restrict__ Wtl) {
    int idx = blockIdx.x * 256 + threadIdx.x;   // 65536 total
    int c = idx >> 9, k = idx & 511;
    float v = W1[(size_t)k * NH + c];
    unsigned short hi = f2b(v);
    Wth[(size_t)c * NF + k] = hi;
    Wtl[(size_t)c * NF + k] = f2b(v - b2f(hi));
}

// ---------------- GEMM1 via MFMA split-bf16, BK=32, reg-prefetch ----------------
// hb[N,128](bf16) = x[N,512] @ W1[512,128]; 128x128 C-tile, 4 waves 2x2.

__global__ __launch_bounds__(256, 3) void k_gemm1(const float* __restrict__ x,
        const unsigned short* __restrict__ Wth, const unsigned short* __restrict__ Wtl,
        unsigned short* __restrict__ hb) {
    __shared__ __align__(16) char smem[4 * 128 * RS];   // 40960 B
    char* Ah = smem;
    char* Al = smem + 128 * RS;
    char* Bh = smem + 2 * 128 * RS;
    char* Bl = smem + 3 * 128 * RS;

    const int tid = threadIdx.x;
    const int r0 = blockIdx.x * 128;
    const int lane = tid & 63, wid = tid >> 6;
    const int wm = wid >> 1, wn = wid & 1;
    const int l15 = lane & 15, lg = lane >> 4;

    // staging coords: X: 8 lanes cover one 128B row-chunk (coalesced)
    const int xr = tid >> 3;          // 0..31
    const int xc = (tid & 7) * 4;     // f32 col
    const int wr = tid >> 2;          // 0..63
    const int wc = (tid & 3) * 8;     // bf16 col

    float4 xv[4];
    ushort8 wvh[2], wvl[2];

    auto loadT = [&](int kc) {
        #pragma unroll
        for (int i = 0; i < 4; i++) {
            int gr = r0 + i * 32 + xr;
            xv[i] = (gr < NN) ? *(const float4*)&x[(size_t)gr * NF + kc + xc]
                              : make_float4(0.f, 0.f, 0.f, 0.f);
        }
        #pragma unroll
        for (int i = 0; i < 2; i++) {
            int c = i * 64 + wr;
            wvh[i] = *(const ushort8*)&Wth[(size_t)c * NF + kc + wc];
            wvl[i] = *(const ushort8*)&Wtl[(size_t)c * NF + kc + wc];
        }
    };
    auto writeT = [&]() {
        #pragma unroll
        for (int i = 0; i < 4; i++) {
            int row = i * 32 + xr;
            int b = row * RS + xc * 2;
            ushort4 hi, lo;
            hi.x = f2b(xv[i].x); lo.x = f2b(xv[i].x - b2f(hi.x));
            hi.y = f2b(xv[i].y); lo.y = f2b(xv[i].y - b2f(hi.y));
            hi.z = f2b(xv[i].z); lo.z = f2b(xv[i].z - b2f(hi.z));
            hi.w = f2b(xv[i].w); lo.w = f2b(xv[i].w - b2f(hi.w));
            *(ushort4*)(Ah + b) = hi;
            *(ushort4*)(Al + b) = lo;
        }
        #pragma unroll
        for (int i = 0; i < 2; i++) {
            int row = i * 64 + wr;
            int b = row * RS + wc * 2;
            *(ushort8*)(Bh + b) = wvh[i];
            *(ushort8*)(Bl + b) = wvl[i];
        }
    };

    f32x4 acc[4][4];
    const f32x4 z = {0.f, 0.f, 0.f, 0.f};
    #pragma unroll
    for (int m = 0; m < 4; m++)
        #pragma unroll
        for (int n = 0; n < 4; n++) acc[m][n] = z;

    loadT(0);
    writeT();
    __syncthreads();

    for (int t = 0; t < NF / BK; t++) {
        short8 ah[4], al[4], bh[4], bl[4];
        #pragma unroll
        for (int m = 0; m < 4; m++) {
            int ar = wm * 64 + m * 16 + l15;
            int b = ar * RS + lg * 16;
            ah[m] = *(const short8*)(Ah + b);
            al[m] = *(const short8*)(Al + b);
        }
        #pragma unroll
        for (int n = 0; n < 4; n++) {
            int br = wn * 64 + n * 16 + l15;
            int b = br * RS + lg * 16;
            bh[n] = *(const short8*)(Bh + b);
            bl[n] = *(const short8*)(Bl + b);
        }
        if (t < NF / BK - 1) loadT((t + 1) * BK);   // issue next-tile loads -> regs
        __builtin_amdgcn_s_setprio(1);
        #pragma unroll
        for (int m = 0; m < 4; m++)
            #pragma unroll
            for (int n = 0; n < 4; n++) {
                acc[m][n] = __builtin_amdgcn_mfma_f32_16x16x32_bf16(ah[m], bh[n], acc[m][n], 0, 0, 0);
                acc[m][n] = __builtin_amdgcn_mfma_f32_16x16x32_bf16(ah[m], bl[n], acc[m][n], 0, 0, 0);
                acc[m][n] = __builtin_amdgcn_mfma_f32_16x16x32_bf16(al[m], bh[n], acc[m][n], 0, 0, 0);
            }
        __builtin_amdgcn_s_setprio(0);
        __syncthreads();
        if (t < NF / BK - 1) { writeT(); __syncthreads(); }
    }

    // C/D layout: col = lane&15, row = (lane>>4)*4 + j
    #pragma unroll
    for (int m = 0; m < 4; m++) {
        int grb = r0 + wm * 64 + m * 16 + lg * 4;
        #pragma unroll
        for (int n = 0; n < 4; n++) {
            int gc = wn * 64 + n * 16 + l15;
            #pragma unroll
            for (int j = 0; j < 4; j++) {
                int gr = grb + j;
                if (gr < NN) hb[(size_t)gr * NH + gc] = f2b(acc[m][n][j]);
            }
        }
    }
}

// ---------------- aggregation 1: CSR gather (bf16 h), fused bias+relu ----------

__global__ __launch_bounds__(256) void k_agg1_gather(const unsigned short* __restrict__ hb,
        const float* __restrict__ dinv, const int* __restrict__ ptr,
        const int2* __restrict__ csre, const float* __restrict__ b1,
        float* __restrict__ hagg) {
    int tid = blockIdx.x * 256 + threadIdx.x;
    int n = tid >> 5;
    if (n >= NN) return;
    int j = (tid & 31) * 4;
    float d = dinv[n]; float s = d * d;
    ushort4 v = *(const ushort4*)&hb[(size_t)n * NH + j];
    float4 acc = make_float4(b2f(v.x) * s, b2f(v.y) * s, b2f(v.z) * s, b2f(v.w) * s);
    int p0 = ptr[n], p1 = ptr[n + 1];
    for (int p = p0; p < p1; p++) {
        int2 e = csre[p];
        float cf = __int_as_float(e.y);
        ushort4 u = *(const ushort4*)&hb[(size_t)e.x * NH + j];
        acc.x = fmaf(cf, b2f(u.x), acc.x);
        acc.y = fmaf(cf, b2f(u.y), acc.y);
        acc.z = fmaf(cf, b2f(u.z), acc.z);
        acc.w = fmaf(cf, b2f(u.w), acc.w);
    }
    float4 b = *(const float4*)&b1[j];
    acc.x = fmaxf(acc.x + b.x, 0.f);
    acc.y = fmaxf(acc.y + b.y, 0.f);
    acc.z = fmaxf(acc.z + b.z, 0.f);
    acc.w = fmaxf(acc.w + b.w, 0.f);
    *(float4*)&hagg[(size_t)n * NH + j] = acc;
}

// ---------------- GEMM2: h2[N,20] = hagg[N,128] @ W2[128,20] ----------------

__global__ __launch_bounds__(256) void k_gemm2(const float* __restrict__ hr,
        const float* __restrict__ W2, float* __restrict__ h2) {
    __shared__ float xs[128][132];
    __shared__ float ws[128][20];
    int tid = threadIdx.x;
    int r0 = blockIdx.x * 128;
    #pragma unroll
    for (int it = 0; it < 3; it++) {
        int idx = it * 256 + tid;
        if (idx < 640) {
            int rr = idx / 5, cg = idx % 5;
            *(float4*)&ws[rr][cg * 4] = *(const float4*)&W2[(size_t)rr * NC + cg * 4];
        }
    }
    #pragma unroll
    for (int it = 0; it < 16; it++) {
        int rr = it * 8 + (tid >> 5);
        int cc = (tid & 31) * 4;
        int gr = r0 + rr;
        float4 v = make_float4(0.f, 0.f, 0.f, 0.f);
        if (gr < NN) v = *(const float4*)&hr[(size_t)gr * NH + cc];
        *(float4*)&xs[rr][cc] = v;
    }
    __syncthreads();
    int r  = tid >> 1;
    int c0 = (tid & 1) * 10;
    float acc[10] = {};
    for (int k = 0; k < NH; k++) {
        float a = xs[r][k];
        #pragma unroll
        for (int j = 0; j < 5; j++) {
            float2 b = *(const float2*)&ws[k][c0 + 2 * j];
            acc[2 * j]     = fmaf(a, b.x, acc[2 * j]);
            acc[2 * j + 1] = fmaf(a, b.y, acc[2 * j + 1]);
        }
    }
    int gr = r0 + r;
    if (gr < NN) {
        #pragma unroll
        for (int j = 0; j < 5; j++)
            *(float2*)&h2[(size_t)gr * NC + c0 + 2 * j] = make_float2(acc[2 * j], acc[2 * j + 1]);
    }
}

// ---------------- aggregation 2 + bias + log_softmax, fully fused -----------

__global__ __launch_bounds__(256) void k_agg2_fused(const float* __restrict__ h2,
        const float* __restrict__ dinv, const int* __restrict__ ptr,
        const int2* __restrict__ csre, const float* __restrict__ b2,
        float* __restrict__ out) {
    int n = blockIdx.x * 256 + threadIdx.x;
    if (n >= NN) return;
    float acc[20];
    float d = dinv[n]; float s = d * d;
    #pragma unroll
    for (int g = 0; g < 5; g++) {
        float4 v = *(const float4*)&h2[(size_t)n * NC + g * 4];
        acc[g * 4 + 0] = v.x * s; acc[g * 4 + 1] = v.y * s;
        acc[g * 4 + 2] = v.z * s; acc[g * 4 + 3] = v.w * s;
    }
    int p0 = ptr[n], p1 = ptr[n + 1];
    for (int p = p0; p < p1; p++) {
        int2 e = csre[p];
        float cf = __int_as_float(e.y);
        const float* hr = &h2[(size_t)e.x * NC];
        #pragma unroll
        for (int g = 0; g < 5; g++) {
            float4 v = *(const float4*)&hr[g * 4];
            acc[g * 4 + 0] = fmaf(cf, v.x, acc[g * 4 + 0]);
            acc[g * 4 + 1] = fmaf(cf, v.y, acc[g * 4 + 1]);
            acc[g * 4 + 2] = fmaf(cf, v.z, acc[g * 4 + 2]);
            acc[g * 4 + 3] = fmaf(cf, v.w, acc[g * 4 + 3]);
        }
    }
    #pragma unroll
    for (int j = 0; j < 20; j++) acc[j] += b2[j];
    float m = acc[0];
    #pragma unroll
    for (int j = 1; j < 20; j++) m = fmaxf(m, acc[j]);
    float ssum = 0.f;
    #pragma unroll
    for (int j = 0; j < 20; j++) ssum += __expf(acc[j] - m);
    float l = m + __logf(ssum);
    #pragma unroll
    for (int g = 0; g < 5; g++)
        *(float4*)&out[(size_t)n * NC + g * 4] =
            make_float4(acc[g * 4] - l, acc[g * 4 + 1] - l, acc[g * 4 + 2] - l, acc[g * 4 + 3] - l);
}

// ---------------- launch ----------------

extern "C" void kernel_launch(void* const* d_in, const int* in_sizes, int n_in,
                              void* d_out, int out_size, void* d_ws, size_t ws_size,
                              hipStream_t stream) {
    const float* x  = (const float*)d_in[0];
    const int*   ei = (const int*)d_in[1];
    const float* ew = (const float*)d_in[2];
    const float* W1 = (const float*)d_in[3];
    const float* b1 = (const float*)d_in[4];
    const float* W2 = (const float*)d_in[5];
    const float* b2 = (const float*)d_in[6];
    float* out = (float*)d_out;

    char* ws = (char*)d_ws;
    float* dinv  = (float*)(ws + 0);              // NN f32
    int*   cnt   = (int*)  (ws + 409600);         // NN i32
    int*   ptr   = (int*)  (ws + 819200);         // NN+1 i32
    int*   cursor= (int*)  (ws + 1228800);        // NN i32
    int*   part  = (int*)  (ws + 1638400);        // SCAN_NBLK i32
    int2*  csre  = (int2*) (ws + 1703936);        // NE int2 (12.8 MB)
    unsigned short* hb = (unsigned short*)(ws + 14680064);   // NN*NH bf16 (25.6 MB)
    float* hagg  = (float*)(ws + 41943040);       // NN*NH f32 (51.2 MB)
    float* h2    = (float*)(ws + 94371840);       // NN*NC f32 (8 MB)
    unsigned short* Wth = (unsigned short*)(ws + 104857600);          // 128 KB
    unsigned short* Wtl = (unsigned short*)(ws + 104857600 + 131072); // 128 KB

    dim3 b(256);
    k_init      <<<(NN + 255) / 256, b, 0, stream>>>(dinv, cnt);
    k_deg_count <<<(NE + 255) / 256, b, 0, stream>>>(ei, ew, dinv, cnt);
    k_dinv      <<<(NN + 255) / 256, b, 0, stream>>>(dinv);
    k_scan_a    <<<SCAN_NBLK, b, 0, stream>>>(cnt, part);
    k_scan_b    <<<1, 64, 0, stream>>>(part);
    k_scan_c    <<<SCAN_NBLK, b, 0, stream>>>(cnt, part, ptr, cursor);
    k_scatter   <<<(NE + 255) / 256, b, 0, stream>>>(ei, ew, dinv, cursor, csre);

    k_splitW    <<<256, b, 0, stream>>>(W1, Wth, Wtl);
    k_gemm1     <<<(NN + 127) / 128, b, 0, stream>>>(x, Wth, Wtl, hb);
    k_agg1_gather<<<(int)(((long)NN * 32 + 255) / 256), b, 0, stream>>>(hb, dinv, ptr, csre, b1, hagg);
    k_gemm2     <<<(NN + 127) / 128, b, 0, stream>>>(hagg, W2, h2);
    k_agg2_fused<<<(NN + 255) / 256, b, 0, stream>>>(h2, dinv, ptr, csre, b2, out);
}

// Round 5
// 738.086 us; speedup vs baseline: 5.2864x; 1.0661x over previous
//
#include <hip/hip_runtime.h>
#include <hip/hip_bf16.h>

#define NN 100000   // nodes
#define NE 1600000  // edges
#define NF 512      // in features
#define NH 128      // hidden
#define NC 20       // classes

#define SCAN_NBLK 98   // ceil(NN/1024)
#define BK 32

typedef __attribute__((ext_vector_type(8))) short short8;
typedef __attribute__((ext_vector_type(8))) unsigned short ushort8;
typedef __attribute__((ext_vector_type(4))) float f32x4;

static __device__ __forceinline__ unsigned short f2b(float x) {  // f32 -> bf16 RNE
    unsigned u = __float_as_uint(x);
    u += 0x7fffu + ((u >> 16) & 1u);
    return (unsigned short)(u >> 16);
}
static __device__ __forceinline__ float b2f(unsigned short b) {
    return __uint_as_float((unsigned)b << 16);
}

// ---------------- degree + in-degree count ----------------

__global__ __launch_bounds__(256) void k_init(float* __restrict__ deg, int* __restrict__ cnt) {
    int i = blockIdx.x * 256 + threadIdx.x;
    if (i < NN) { deg[i] = 1.0f; cnt[i] = 0; }   // self-loop weight 1
}

__global__ __launch_bounds__(256) void k_deg_count(const int* __restrict__ ei,
        const float* __restrict__ ew, float* __restrict__ deg, int* __restrict__ cnt) {
    int e = blockIdx.x * 256 + threadIdx.x;
    if (e < NE) {
        int c = ei[NE + e];
        unsafeAtomicAdd(&deg[c], ew[e]);
        atomicAdd(&cnt[c], 1);
    }
}

__global__ __launch_bounds__(256) void k_dinv(float* __restrict__ deg) {
    int i = blockIdx.x * 256 + threadIdx.x;
    if (i < NN) { float d = deg[i]; deg[i] = d > 0.f ? rsqrtf(d) : 0.f; }
}

// ---------------- exclusive scan of cnt -> ptr ----------------

__global__ __launch_bounds__(256) void k_scan_a(const int* __restrict__ cnt, int* __restrict__ part) {
    __shared__ int s[256];
    int b = blockIdx.x, t = threadIdx.x;
    int base = b * 1024 + t * 4;
    int sum = 0;
    #pragma unroll
    for (int i = 0; i < 4; i++) { int idx = base + i; if (idx < NN) sum += cnt[idx]; }
    s[t] = sum; __syncthreads();
    for (int o = 128; o; o >>= 1) { if (t < o) s[t] += s[t + o]; __syncthreads(); }
    if (t == 0) part[b] = s[0];
}

__global__ void k_scan_b(int* __restrict__ part) {
    if (threadIdx.x == 0 && blockIdx.x == 0) {
        int acc = 0;
        for (int i = 0; i < SCAN_NBLK; i++) { int v = part[i]; part[i] = acc; acc += v; }
    }
}

__global__ __launch_bounds__(256) void k_scan_c(const int* __restrict__ cnt,
        const int* __restrict__ part, int* __restrict__ ptr, int* __restrict__ cursor) {
    __shared__ int s[256];
    int b = blockIdx.x, t = threadIdx.x;
    int base = b * 1024 + t * 4;
    int v[4]; int sum = 0;
    #pragma unroll
    for (int i = 0; i < 4; i++) { int idx = base + i; v[i] = (idx < NN) ? cnt[idx] : 0; sum += v[i]; }
    s[t] = sum; __syncthreads();
    for (int o = 1; o < 256; o <<= 1) {
        int x = (t >= o) ? s[t - o] : 0;
        __syncthreads();
        s[t] += x;
        __syncthreads();
    }
    int off = part[b] + s[t] - sum;
    #pragma unroll
    for (int i = 0; i < 4; i++) {
        int idx = base + i;
        if (idx < NN) { ptr[idx] = off; cursor[idx] = off; off += v[i]; }
    }
    if (b == 0 && t == 0) ptr[NN] = NE;
}

// ---------------- CSR scatter (int atomics only) ----------------

__global__ __launch_bounds__(256) void k_scatter(const int* __restrict__ ei,
        const float* __restrict__ ew, const float* __restrict__ dinv,
        int* __restrict__ cursor, int2* __restrict__ csre) {
    int e = blockIdx.x * 256 + threadIdx.x;
    if (e >= NE) return;
    int r = ei[e], c = ei[NE + e];
    float cf = dinv[r] * ew[e] * dinv[c];
    int pos = atomicAdd(&cursor[c], 1);
    csre[pos] = make_int2(r, __float_as_int(cf));
}

// ---------------- W1 split+transpose: Wt_h/Wt_l[128][512] bf16 ----------------

__global__ __launch_bounds__(256) void k_splitW(const float* __restrict__ W1,
        unsigned short* __restrict__ Wth, unsigned short* __restrict__ Wtl) {
    int idx = blockIdx.x * 256 + threadIdx.x;   // 65536 total
    int c = idx >> 9, k = idx & 511;
    float v = W1[(size_t)k * NH + c];
    unsigned short hi = f2b(v);
    Wth[(size_t)c * NF + k] = hi;
    Wtl[(size_t)c * NF + k] = f2b(v - b2f(hi));
}

// ---------------- GEMM1 via MFMA split-bf16 ----------------
// hb[N,128](bf16) = x[N,512] @ W1[512,128].
// Block: 64x128 C-tile, 4 waves 2x2, per-wave 32x64 (acc[2][4] = 32 regs ->
// VGPR+AGPR <= 128 -> 16 waves/CU). BK=32. LDS rows are 128B = [32k hi | 32k lo]
// bf16 with 16B-slot XOR swizzle (slot ^= row&7): zero conflicts (R3 scheme).

__global__ __launch_bounds__(256) void k_gemm1(const float* __restrict__ x,
        const unsigned short* __restrict__ Wth, const unsigned short* __restrict__ Wtl,
        unsigned short* __restrict__ hb) {
    __shared__ __align__(16) char smem[(64 + 128) * 128];   // 24576 B
    char* As = smem;             // [64 rows][128B]
    char* Bs = smem + 64 * 128;  // [128 c-rows][128B]

    const int tid = threadIdx.x;
    const int r0 = blockIdx.x * 64;
    const int lane = tid & 63, wid = tid >> 6;
    const int wm = wid >> 1, wn = wid & 1;
    const int l15 = lane & 15, lg = lane >> 4;

    // A staging: row = tid>>2 (0..63), quarter aq = tid&3 -> 8 f32 of k
    const int ar = tid >> 2, aq = tid & 3;
    // B staging: c-row = tid>>1 (0..127), half bh2 = tid&1 -> 16 bf16 of k
    const int bc = tid >> 1, bh2 = tid & 1;

    f32x4 acc[2][4];
    const f32x4 z = {0.f, 0.f, 0.f, 0.f};
    #pragma unroll
    for (int m = 0; m < 2; m++)
        #pragma unroll
        for (int n = 0; n < 4; n++) acc[m][n] = z;

    for (int t = 0; t < NF / BK; t++) {
        const int kc = t * BK;
        // ---- stage A: 8 f32 -> hi/lo ushort8, slots aq and 4+aq ----
        {
            int gr = r0 + ar;
            float4 v0 = make_float4(0.f,0.f,0.f,0.f), v1 = v0;
            if (gr < NN) {
                const float* p = &x[(size_t)gr * NF + kc + aq * 8];
                v0 = *(const float4*)p;
                v1 = *(const float4*)(p + 4);
            }
            ushort8 hi, lo;
            float vv[8] = {v0.x, v0.y, v0.z, v0.w, v1.x, v1.y, v1.z, v1.w};
            #pragma unroll
            for (int i = 0; i < 8; i++) {
                unsigned short h = f2b(vv[i]);
                hi[i] = h;
                lo[i] = f2b(vv[i] - b2f(h));
            }
            int base = ar * 128;
            int sw = (ar & 7) << 4;
            *(ushort8*)(As + base + ((aq << 4) ^ sw)) = hi;
            *(ushort8*)(As + base + (((4 + aq) << 4) ^ sw)) = lo;
        }
        // ---- stage B: pre-split W, 16 bf16 hi + 16 lo, slots 2*bh2..  ----
        {
            const size_t gofs = (size_t)bc * NF + kc + bh2 * 16;
            ushort8 h0 = *(const ushort8*)&Wth[gofs];
            ushort8 h1 = *(const ushort8*)&Wth[gofs + 8];
            ushort8 l0 = *(const ushort8*)&Wtl[gofs];
            ushort8 l1 = *(const ushort8*)&Wtl[gofs + 8];
            int base = bc * 128;
            int sw = (bc & 7) << 4;
            int s0 = bh2 * 2;
            *(ushort8*)(Bs + base + ((s0 << 4) ^ sw))           = h0;
            *(ushort8*)(Bs + base + (((s0 + 1) << 4) ^ sw))     = h1;
            *(ushort8*)(Bs + base + (((4 + s0) << 4) ^ sw))     = l0;
            *(ushort8*)(Bs + base + (((5 + s0) << 4) ^ sw))     = l1;
        }
        __syncthreads();

        // ---- fragments ----
        short8 ah[2], al[2], bh[4], bl[4];
        #pragma unroll
        for (int m = 0; m < 2; m++) {
            int row = wm * 32 + m * 16 + l15;
            int base = row * 128, sw = (row & 7) << 4;
            ah[m] = *(const short8*)(As + base + ((lg << 4) ^ sw));
            al[m] = *(const short8*)(As + base + (((4 + lg) << 4) ^ sw));
        }
        #pragma unroll
        for (int n = 0; n < 4; n++) {
            int row = wn * 64 + n * 16 + l15;
            int base = row * 128, sw = (row & 7) << 4;
            bh[n] = *(const short8*)(Bs + base + ((lg << 4) ^ sw));
            bl[n] = *(const short8*)(Bs + base + (((4 + lg) << 4) ^ sw));
        }
        __builtin_amdgcn_s_setprio(1);
        #pragma unroll
        for (int m = 0; m < 2; m++)
            #pragma unroll
            for (int n = 0; n < 4; n++) {
                acc[m][n] = __builtin_amdgcn_mfma_f32_16x16x32_bf16(ah[m], bh[n], acc[m][n], 0, 0, 0);
                acc[m][n] = __builtin_amdgcn_mfma_f32_16x16x32_bf16(ah[m], bl[n], acc[m][n], 0, 0, 0);
                acc[m][n] = __builtin_amdgcn_mfma_f32_16x16x32_bf16(al[m], bh[n], acc[m][n], 0, 0, 0);
            }
        __builtin_amdgcn_s_setprio(0);
        __syncthreads();
    }

    // ---- store: C/D layout col = lane&15, row = (lane>>4)*4 + j ----
    #pragma unroll
    for (int m = 0; m < 2; m++) {
        int grb = r0 + wm * 32 + m * 16 + lg * 4;
        #pragma unroll
        for (int n = 0; n < 4; n++) {
            int gc = wn * 64 + n * 16 + l15;
            #pragma unroll
            for (int j = 0; j < 4; j++) {
                int gr = grb + j;
                if (gr < NN) hb[(size_t)gr * NH + gc] = f2b(acc[m][n][j]);
            }
        }
    }
}

// ---------------- aggregation 1: CSR gather (bf16 h), fused bias+relu ----------

__global__ __launch_bounds__(256) void k_agg1_gather(const unsigned short* __restrict__ hb,
        const float* __restrict__ dinv, const int* __restrict__ ptr,
        const int2* __restrict__ csre, const float* __restrict__ b1,
        float* __restrict__ hagg) {
    int tid = blockIdx.x * 256 + threadIdx.x;
    int n = tid >> 5;
    if (n >= NN) return;
    int j = (tid & 31) * 4;
    float d = dinv[n]; float s = d * d;
    ushort4 v = *(const ushort4*)&hb[(size_t)n * NH + j];
    float4 acc = make_float4(b2f(v.x) * s, b2f(v.y) * s, b2f(v.z) * s, b2f(v.w) * s);
    int p0 = ptr[n], p1 = ptr[n + 1];
    for (int p = p0; p < p1; p++) {
        int2 e = csre[p];
        float cf = __int_as_float(e.y);
        ushort4 u = *(const ushort4*)&hb[(size_t)e.x * NH + j];
        acc.x = fmaf(cf, b2f(u.x), acc.x);
        acc.y = fmaf(cf, b2f(u.y), acc.y);
        acc.z = fmaf(cf, b2f(u.z), acc.z);
        acc.w = fmaf(cf, b2f(u.w), acc.w);
    }
    float4 b = *(const float4*)&b1[j];
    acc.x = fmaxf(acc.x + b.x, 0.f);
    acc.y = fmaxf(acc.y + b.y, 0.f);
    acc.z = fmaxf(acc.z + b.z, 0.f);
    acc.w = fmaxf(acc.w + b.w, 0.f);
    *(float4*)&hagg[(size_t)n * NH + j] = acc;
}

// ---------------- GEMM2: h2[N,20] = hagg[N,128] @ W2[128,20] ----------------

__global__ __launch_bounds__(256) void k_gemm2(const float* __restrict__ hr,
        const float* __restrict__ W2, float* __restrict__ h2) {
    __shared__ float xs[128][132];
    __shared__ float ws[128][20];
    int tid = threadIdx.x;
    int r0 = blockIdx.x * 128;
    #pragma unroll
    for (int it = 0; it < 3; it++) {
        int idx = it * 256 + tid;
        if (idx < 640) {
            int rr = idx / 5, cg = idx % 5;
            *(float4*)&ws[rr][cg * 4] = *(const float4*)&W2[(size_t)rr * NC + cg * 4];
        }
    }
    #pragma unroll
    for (int it = 0; it < 16; it++) {
        int rr = it * 8 + (tid >> 5);
        int cc = (tid & 31) * 4;
        int gr = r0 + rr;
        float4 v = make_float4(0.f, 0.f, 0.f, 0.f);
        if (gr < NN) v = *(const float4*)&hr[(size_t)gr * NH + cc];
        *(float4*)&xs[rr][cc] = v;
    }
    __syncthreads();
    int r  = tid >> 1;
    int c0 = (tid & 1) * 10;
    float acc[10] = {};
    for (int k = 0; k < NH; k++) {
        float a = xs[r][k];
        #pragma unroll
        for (int j = 0; j < 5; j++) {
            float2 b = *(const float2*)&ws[k][c0 + 2 * j];
            acc[2 * j]     = fmaf(a, b.x, acc[2 * j]);
            acc[2 * j + 1] = fmaf(a, b.y, acc[2 * j + 1]);
        }
    }
    int gr = r0 + r;
    if (gr < NN) {
        #pragma unroll
        for (int j = 0; j < 5; j++)
            *(float2*)&h2[(size_t)gr * NC + c0 + 2 * j] = make_float2(acc[2 * j], acc[2 * j + 1]);
    }
}

// ---------------- aggregation 2 + bias + log_softmax, fully fused -----------

__global__ __launch_bounds__(256) void k_agg2_fused(const float* __restrict__ h2,
        const float* __restrict__ dinv, const int* __restrict__ ptr,
        const int2* __restrict__ csre, const float* __restrict__ b2,
        float* __restrict__ out) {
    int n = blockIdx.x * 256 + threadIdx.x;
    if (n >= NN) return;
    float acc[20];
    float d = dinv[n]; float s = d * d;
    #pragma unroll
    for (int g = 0; g < 5; g++) {
        float4 v = *(const float4*)&h2[(size_t)n * NC + g * 4];
        acc[g * 4 + 0] = v.x * s; acc[g * 4 + 1] = v.y * s;
        acc[g * 4 + 2] = v.z * s; acc[g * 4 + 3] = v.w * s;
    }
    int p0 = ptr[n], p1 = ptr[n + 1];
    for (int p = p0; p < p1; p++) {
        int2 e = csre[p];
        float cf = __int_as_float(e.y);
        const float* hr = &h2[(size_t)e.x * NC];
        #pragma unroll
        for (int g = 0; g < 5; g++) {
            float4 v = *(const float4*)&hr[g * 4];
            acc[g * 4 + 0] = fmaf(cf, v.x, acc[g * 4 + 0]);
            acc[g * 4 + 1] = fmaf(cf, v.y, acc[g * 4 + 1]);
            acc[g * 4 + 2] = fmaf(cf, v.z, acc[g * 4 + 2]);
            acc[g * 4 + 3] = fmaf(cf, v.w, acc[g * 4 + 3]);
        }
    }
    #pragma unroll
    for (int j = 0; j < 20; j++) acc[j] += b2[j];
    float m = acc[0];
    #pragma unroll
    for (int j = 1; j < 20; j++) m = fmaxf(m, acc[j]);
    float ssum = 0.f;
    #pragma unroll
    for (int j = 0; j < 20; j++) ssum += __expf(acc[j] - m);
    float l = m + __logf(ssum);
    #pragma unroll
    for (int g = 0; g < 5; g++)
        *(float4*)&out[(size_t)n * NC + g * 4] =
            make_float4(acc[g * 4] - l, acc[g * 4 + 1] - l, acc[g * 4 + 2] - l, acc[g * 4 + 3] - l);
}

// ---------------- launch ----------------

extern "C" void kernel_launch(void* const* d_in, const int* in_sizes, int n_in,
                              void* d_out, int out_size, void* d_ws, size_t ws_size,
                              hipStream_t stream) {
    const float* x  = (const float*)d_in[0];
    const int*   ei = (const int*)d_in[1];
    const float* ew = (const float*)d_in[2];
    const float* W1 = (const float*)d_in[3];
    const float* b1 = (const float*)d_in[4];
    const float* W2 = (const float*)d_in[5];
    const float* b2 = (const float*)d_in[6];
    float* out = (float*)d_out;

    char* ws = (char*)d_ws;
    float* dinv  = (float*)(ws + 0);              // NN f32
    int*   cnt   = (int*)  (ws + 409600);         // NN i32
    int*   ptr   = (int*)  (ws + 819200);         // NN+1 i32
    int*   cursor= (int*)  (ws + 1228800);        // NN i32
    int*   part  = (int*)  (ws + 1638400);        // SCAN_NBLK i32
    int2*  csre  = (int2*) (ws + 1703936);        // NE int2 (12.8 MB)
    unsigned short* hb = (unsigned short*)(ws + 14680064);   // NN*NH bf16 (25.6 MB)
    float* hagg  = (float*)(ws + 41943040);       // NN*NH f32 (51.2 MB)
    float* h2    = (float*)(ws + 94371840);       // NN*NC f32 (8 MB)
    unsigned short* Wth = (unsigned short*)(ws + 104857600);          // 128 KB
    unsigned short* Wtl = (unsigned short*)(ws + 104857600 + 131072); // 128 KB

    dim3 b(256);
    k_init      <<<(NN + 255) / 256, b, 0, stream>>>(dinv, cnt);
    k_deg_count <<<(NE + 255) / 256, b, 0, stream>>>(ei, ew, dinv, cnt);
    k_dinv      <<<(NN + 255) / 256, b, 0, stream>>>(dinv);
    k_scan_a    <<<SCAN_NBLK, b, 0, stream>>>(cnt, part);
    k_scan_b    <<<1, 64, 0, stream>>>(part);
    k_scan_c    <<<SCAN_NBLK, b, 0, stream>>>(cnt, part, ptr, cursor);
    k_scatter   <<<(NE + 255) / 256, b, 0, stream>>>(ei, ew, dinv, cursor, csre);

    k_splitW    <<<256, b, 0, stream>>>(W1, Wth, Wtl);
    k_gemm1     <<<(NN + 63) / 64, b, 0, stream>>>(x, Wth, Wtl, hb);
    k_agg1_gather<<<(int)(((long)NN * 32 + 255) / 256), b, 0, stream>>>(hb, dinv, ptr, csre, b1, hagg);
    k_gemm2     <<<(NN + 127) / 128, b, 0, stream>>>(hagg, W2, h2);
    k_agg2_fused<<<(NN + 255) / 256, b, 0, stream>>>(h2, dinv, ptr, csre, b2, out);
}

// Round 7
// 722.940 us; speedup vs baseline: 5.3972x; 1.0210x over previous
//
#include <hip/hip_runtime.h>
#include <hip/hip_bf16.h>

#define NN 100000   // nodes
#define NE 1600000  // edges
#define NF 512      // in features
#define NH 128      // hidden
#define NC 20       // classes

#define SCAN_NBLK 98   // ceil(NN/1024)
#define BK 32

typedef __attribute__((ext_vector_type(8))) short short8;
typedef __attribute__((ext_vector_type(8))) unsigned short ushort8;
typedef __attribute__((ext_vector_type(4))) float f32x4;

static __device__ __forceinline__ unsigned short f2b(float x) {  // f32 -> bf16 RNE
    unsigned u = __float_as_uint(x);
    u += 0x7fffu + ((u >> 16) & 1u);
    return (unsigned short)(u >> 16);
}
static __device__ __forceinline__ float b2f(unsigned short b) {
    return __uint_as_float((unsigned)b << 16);
}

// ---------------- in-degree count (int atomics only) ----------------

__global__ __launch_bounds__(256) void k_init(int* __restrict__ cnt) {
    int i = blockIdx.x * 256 + threadIdx.x;
    if (i < NN) cnt[i] = 0;
}

__global__ __launch_bounds__(256) void k_count(const int* __restrict__ ei,
        int* __restrict__ cnt) {
    int e = blockIdx.x * 256 + threadIdx.x;
    if (e < NE) atomicAdd(&cnt[ei[NE + e]], 1);
}

// ---------------- exclusive scan of cnt -> ptr ----------------

__global__ __launch_bounds__(256) void k_scan_a(const int* __restrict__ cnt, int* __restrict__ part) {
    __shared__ int s[256];
    int b = blockIdx.x, t = threadIdx.x;
    int base = b * 1024 + t * 4;
    int sum = 0;
    #pragma unroll
    for (int i = 0; i < 4; i++) { int idx = base + i; if (idx < NN) sum += cnt[idx]; }
    s[t] = sum; __syncthreads();
    for (int o = 128; o; o >>= 1) { if (t < o) s[t] += s[t + o]; __syncthreads(); }
    if (t == 0) part[b] = s[0];
}

__global__ void k_scan_b(int* __restrict__ part) {
    if (threadIdx.x == 0 && blockIdx.x == 0) {
        int acc = 0;
        for (int i = 0; i < SCAN_NBLK; i++) { int v = part[i]; part[i] = acc; acc += v; }
    }
}

__global__ __launch_bounds__(256) void k_scan_c(const int* __restrict__ cnt,
        const int* __restrict__ part, int* __restrict__ ptr, int* __restrict__ cursor) {
    __shared__ int s[256];
    int b = blockIdx.x, t = threadIdx.x;
    int base = b * 1024 + t * 4;
    int v[4]; int sum = 0;
    #pragma unroll
    for (int i = 0; i < 4; i++) { int idx = base + i; v[i] = (idx < NN) ? cnt[idx] : 0; sum += v[i]; }
    s[t] = sum; __syncthreads();
    for (int o = 1; o < 256; o <<= 1) {
        int x = (t >= o) ? s[t - o] : 0;
        __syncthreads();
        s[t] += x;
        __syncthreads();
    }
    int off = part[b] + s[t] - sum;
    #pragma unroll
    for (int i = 0; i < 4; i++) {
        int idx = base + i;
        if (idx < NN) { ptr[idx] = off; cursor[idx] = off; off += v[i]; }
    }
    if (b == 0 && t == 0) ptr[NN] = NE;
}

// ---------------- CSR scatter: store (src, raw w) ----------------

__global__ __launch_bounds__(256) void k_scatter(const int* __restrict__ ei,
        const float* __restrict__ ew, int* __restrict__ cursor, int2* __restrict__ csre) {
    int e = blockIdx.x * 256 + threadIdx.x;
    if (e >= NE) return;
    int r = ei[e], c = ei[NE + e];
    int pos = atomicAdd(&cursor[c], 1);
    csre[pos] = make_int2(r, __float_as_int(ew[e]));
}

// ---------------- degree from CSR (no atomics) -> dinv ----------------

__global__ __launch_bounds__(256) void k_deg_csr(const int* __restrict__ ptr,
        const int2* __restrict__ csre, float* __restrict__ dinv) {
    int n = blockIdx.x * 256 + threadIdx.x;
    if (n >= NN) return;
    int p0 = ptr[n], p1 = ptr[n + 1];
    float d = 1.0f;    // self-loop
    for (int p = p0; p < p1; p++) d += __int_as_float(csre[p].y);
    dinv[n] = d > 0.f ? rsqrtf(d) : 0.f;
}

// ---------------- coeff in place: csre.y = dinv[src]*w*dinv[dst] ----------------

__global__ __launch_bounds__(256) void k_coeff_csr(const int* __restrict__ ptr,
        const float* __restrict__ dinv, int2* __restrict__ csre) {
    int n = blockIdx.x * 256 + threadIdx.x;
    if (n >= NN) return;
    int p0 = ptr[n], p1 = ptr[n + 1];
    float dc = dinv[n];
    for (int p = p0; p < p1; p++) {
        int2 e = csre[p];
        csre[p].y = __float_as_int(dinv[e.x] * __int_as_float(e.y) * dc);
    }
}

// ---------------- W1 split+transpose: Wt_h/Wt_l[128][512] bf16 ----------------

__global__ __launch_bounds__(256) void k_splitW(const float* __restrict__ W1,
        unsigned short* __restrict__ Wth, unsigned short* __restrict__ Wtl) {
    int idx = blockIdx.x * 256 + threadIdx.x;   // 65536 total
    int c = idx >> 9, k = idx & 511;
    float v = W1[(size_t)k * NH + c];
    unsigned short hi = f2b(v);
    Wth[(size_t)c * NF + k] = hi;
    Wtl[(size_t)c * NF + k] = f2b(v - b2f(hi));
}

// ---------------- GEMM1 via MFMA split-bf16 ----------------
// hb[N,128](bf16) = x[N,512] @ W1[512,128].
// Block: 64x128 C-tile, 4 waves 2x2, per-wave 32x64 (acc[2][4] = 32 regs).
// BK=32. LDS rows are 128B with 16B-slot XOR swizzle (slot ^= row&7): 0 conflicts.

__global__ __launch_bounds__(256) void k_gemm1(const float* __restrict__ x,
        const unsigned short* __restrict__ Wth, const unsigned short* __restrict__ Wtl,
        unsigned short* __restrict__ hb) {
    __shared__ __align__(16) char smem[(64 + 128) * 128];   // 24576 B
    char* As = smem;             // [64 rows][128B]
    char* Bs = smem + 64 * 128;  // [128 c-rows][128B]

    const int tid = threadIdx.x;
    const int r0 = blockIdx.x * 64;
    const int lane = tid & 63, wid = tid >> 6;
    const int wm = wid >> 1, wn = wid & 1;
    const int l15 = lane & 15, lg = lane >> 4;

    const int ar = tid >> 2, aq = tid & 3;
    const int bc = tid >> 1, bh2 = tid & 1;

    f32x4 acc[2][4];
    const f32x4 z = {0.f, 0.f, 0.f, 0.f};
    #pragma unroll
    for (int m = 0; m < 2; m++)
        #pragma unroll
        for (int n = 0; n < 4; n++) acc[m][n] = z;

    for (int t = 0; t < NF / BK; t++) {
        const int kc = t * BK;
        {
            int gr = r0 + ar;
            float4 v0 = make_float4(0.f,0.f,0.f,0.f), v1 = v0;
            if (gr < NN) {
                const float* p = &x[(size_t)gr * NF + kc + aq * 8];
                v0 = *(const float4*)p;
                v1 = *(const float4*)(p + 4);
            }
            ushort8 hi, lo;
            float vv[8] = {v0.x, v0.y, v0.z, v0.w, v1.x, v1.y, v1.z, v1.w};
            #pragma unroll
            for (int i = 0; i < 8; i++) {
                unsigned short h = f2b(vv[i]);
                hi[i] = h;
                lo[i] = f2b(vv[i] - b2f(h));
            }
            int base = ar * 128;
            int sw = (ar & 7) << 4;
            *(ushort8*)(As + base + ((aq << 4) ^ sw)) = hi;
            *(ushort8*)(As + base + (((4 + aq) << 4) ^ sw)) = lo;
        }
        {
            const size_t gofs = (size_t)bc * NF + kc + bh2 * 16;
            ushort8 h0 = *(const ushort8*)&Wth[gofs];
            ushort8 h1 = *(const ushort8*)&Wth[gofs + 8];
            ushort8 l0 = *(const ushort8*)&Wtl[gofs];
            ushort8 l1 = *(const ushort8*)&Wtl[gofs + 8];
            int base = bc * 128;
            int sw = (bc & 7) << 4;
            int s0 = bh2 * 2;
            *(ushort8*)(Bs + base + ((s0 << 4) ^ sw))           = h0;
            *(ushort8*)(Bs + base + (((s0 + 1) << 4) ^ sw))     = h1;
            *(ushort8*)(Bs + base + (((4 + s0) << 4) ^ sw))     = l0;
            *(ushort8*)(Bs + base + (((5 + s0) << 4) ^ sw))     = l1;
        }
        __syncthreads();

        short8 ah[2], al[2], bh[4], bl[4];
        #pragma unroll
        for (int m = 0; m < 2; m++) {
            int row = wm * 32 + m * 16 + l15;
            int base = row * 128, sw = (row & 7) << 4;
            ah[m] = *(const short8*)(As + base + ((lg << 4) ^ sw));
            al[m] = *(const short8*)(As + base + (((4 + lg) << 4) ^ sw));
        }
        #pragma unroll
        for (int n = 0; n < 4; n++) {
            int row = wn * 64 + n * 16 + l15;
            int base = row * 128, sw = (row & 7) << 4;
            bh[n] = *(const short8*)(Bs + base + ((lg << 4) ^ sw));
            bl[n] = *(const short8*)(Bs + base + (((4 + lg) << 4) ^ sw));
        }
        __builtin_amdgcn_s_setprio(1);
        #pragma unroll
        for (int m = 0; m < 2; m++)
            #pragma unroll
            for (int n = 0; n < 4; n++) {
                acc[m][n] = __builtin_amdgcn_mfma_f32_16x16x32_bf16(ah[m], bh[n], acc[m][n], 0, 0, 0);
                acc[m][n] = __builtin_amdgcn_mfma_f32_16x16x32_bf16(ah[m], bl[n], acc[m][n], 0, 0, 0);
                acc[m][n] = __builtin_amdgcn_mfma_f32_16x16x32_bf16(al[m], bh[n], acc[m][n], 0, 0, 0);
            }
        __builtin_amdgcn_s_setprio(0);
        __syncthreads();
    }

    #pragma unroll
    for (int m = 0; m < 2; m++) {
        int grb = r0 + wm * 32 + m * 16 + lg * 4;
        #pragma unroll
        for (int n = 0; n < 4; n++) {
            int gc = wn * 64 + n * 16 + l15;
            #pragma unroll
            for (int j = 0; j < 4; j++) {
                int gr = grb + j;
                if (gr < NN) hb[(size_t)gr * NH + gc] = f2b(acc[m][n][j]);
            }
        }
    }
}

// ---------------- aggregation 1: CSR gather (bf16 h), fused bias+relu ----------

__global__ __launch_bounds__(256) void k_agg1_gather(const unsigned short* __restrict__ hb,
        const float* __restrict__ dinv, const int* __restrict__ ptr,
        const int2* __restrict__ csre, const float* __restrict__ b1,
        float* __restrict__ hagg) {
    int tid = blockIdx.x * 256 + threadIdx.x;
    int n = tid >> 5;
    if (n >= NN) return;
    int j = (tid & 31) * 4;
    float d = dinv[n]; float s = d * d;
    ushort4 v = *(const ushort4*)&hb[(size_t)n * NH + j];
    float4 acc = make_float4(b2f(v.x) * s, b2f(v.y) * s, b2f(v.z) * s, b2f(v.w) * s);
    int p0 = ptr[n], p1 = ptr[n + 1];
    for (int p = p0; p < p1; p++) {
        int2 e = csre[p];
        float cf = __int_as_float(e.y);
        ushort4 u = *(const ushort4*)&hb[(size_t)e.x * NH + j];
        acc.x = fmaf(cf, b2f(u.x), acc.x);
        acc.y = fmaf(cf, b2f(u.y), acc.y);
        acc.z = fmaf(cf, b2f(u.z), acc.z);
        acc.w = fmaf(cf, b2f(u.w), acc.w);
    }
    float4 b = *(const float4*)&b1[j];
    acc.x = fmaxf(acc.x + b.x, 0.f);
    acc.y = fmaxf(acc.y + b.y, 0.f);
    acc.z = fmaxf(acc.z + b.z, 0.f);
    acc.w = fmaxf(acc.w + b.w, 0.f);
    *(float4*)&hagg[(size_t)n * NH + j] = acc;
}

// ---------------- GEMM2: h2[N,20] = hagg[N,128] @ W2[128,20] ----------------

__global__ __launch_bounds__(256) void k_gemm2(const float* __restrict__ hr,
        const float* __restrict__ W2, float* __restrict__ h2) {
    __shared__ float xs[128][132];
    __shared__ float ws[128][20];
    int tid = threadIdx.x;
    int r0 = blockIdx.x * 128;
    #pragma unroll
    for (int it = 0; it < 3; it++) {
        int idx = it * 256 + tid;
        if (idx < 640) {
            int rr = idx / 5, cg = idx % 5;
            *(float4*)&ws[rr][cg * 4] = *(const float4*)&W2[(size_t)rr * NC + cg * 4];
        }
    }
    #pragma unroll
    for (int it = 0; it < 16; it++) {
        int rr = it * 8 + (tid >> 5);
        int cc = (tid & 31) * 4;
        int gr = r0 + rr;
        float4 v = make_float4(0.f, 0.f, 0.f, 0.f);
        if (gr < NN) v = *(const float4*)&hr[(size_t)gr * NH + cc];
        *(float4*)&xs[rr][cc] = v;
    }
    __syncthreads();
    int r  = tid >> 1;
    int c0 = (tid & 1) * 10;
    float acc[10] = {};
    for (int k = 0; k < NH; k++) {
        float a = xs[r][k];
        #pragma unroll
        for (int j = 0; j < 5; j++) {
            float2 b = *(const float2*)&ws[k][c0 + 2 * j];
            acc[2 * j]     = fmaf(a, b.x, acc[2 * j]);
            acc[2 * j + 1] = fmaf(a, b.y, acc[2 * j + 1]);
        }
    }
    int gr = r0 + r;
    if (gr < NN) {
        #pragma unroll
        for (int j = 0; j < 5; j++)
            *(float2*)&h2[(size_t)gr * NC + c0 + 2 * j] = make_float2(acc[2 * j], acc[2 * j + 1]);
    }
}

// ---------------- aggregation 2 + bias + log_softmax, fully fused -----------

__global__ __launch_bounds__(256) void k_agg2_fused(const float* __restrict__ h2,
        const float* __restrict__ dinv, const int* __restrict__ ptr,
        const int2* __restrict__ csre, const float* __restrict__ b2,
        float* __restrict__ out) {
    int n = blockIdx.x * 256 + threadIdx.x;
    if (n >= NN) return;
    float acc[20];
    float d = dinv[n]; float s = d * d;
    #pragma unroll
    for (int g = 0; g < 5; g++) {
        float4 v = *(const float4*)&h2[(size_t)n * NC + g * 4];
        acc[g * 4 + 0] = v.x * s; acc[g * 4 + 1] = v.y * s;
        acc[g * 4 + 2] = v.z * s; acc[g * 4 + 3] = v.w * s;
    }
    int p0 = ptr[n], p1 = ptr[n + 1];
    for (int p = p0; p < p1; p++) {
        int2 e = csre[p];
        float cf = __int_as_float(e.y);
        const float* hr = &h2[(size_t)e.x * NC];
        #pragma unroll
        for (int g = 0; g < 5; g++) {
            float4 v = *(const float4*)&hr[g * 4];
            acc[g * 4 + 0] = fmaf(cf, v.x, acc[g * 4 + 0]);
            acc[g * 4 + 1] = fmaf(cf, v.y, acc[g * 4 + 1]);
            acc[g * 4 + 2] = fmaf(cf, v.z, acc[g * 4 + 2]);
            acc[g * 4 + 3] = fmaf(cf, v.w, acc[g * 4 + 3]);
        }
    }
    #pragma unroll
    for (int j = 0; j < 20; j++) acc[j] += b2[j];
    float m = acc[0];
    #pragma unroll
    for (int j = 1; j < 20; j++) m = fmaxf(m, acc[j]);
    float ssum = 0.f;
    #pragma unroll
    for (int j = 0; j < 20; j++) ssum += __expf(acc[j] - m);
    float l = m + __logf(ssum);
    #pragma unroll
    for (int g = 0; g < 5; g++)
        *(float4*)&out[(size_t)n * NC + g * 4] =
            make_float4(acc[g * 4] - l, acc[g * 4 + 1] - l, acc[g * 4 + 2] - l, acc[g * 4 + 3] - l);
}

// ---------------- launch ----------------

extern "C" void kernel_launch(void* const* d_in, const int* in_sizes, int n_in,
                              void* d_out, int out_size, void* d_ws, size_t ws_size,
                              hipStream_t stream) {
    const float* x  = (const float*)d_in[0];
    const int*   ei = (const int*)d_in[1];
    const float* ew = (const float*)d_in[2];
    const float* W1 = (const float*)d_in[3];
    const float* b1 = (const float*)d_in[4];
    const float* W2 = (const float*)d_in[5];
    const float* b2 = (const float*)d_in[6];
    float* out = (float*)d_out;

    char* ws = (char*)d_ws;
    float* dinv  = (float*)(ws + 0);              // NN f32
    int*   cnt   = (int*)  (ws + 409600);         // NN i32
    int*   ptr   = (int*)  (ws + 819200);         // NN+1 i32
    int*   cursor= (int*)  (ws + 1228800);        // NN i32
    int*   part  = (int*)  (ws + 1638400);        // SCAN_NBLK i32
    int2*  csre  = (int2*) (ws + 1703936);        // NE int2 (12.8 MB)
    unsigned short* hb = (unsigned short*)(ws + 14680064);   // NN*NH bf16 (25.6 MB)
    float* hagg  = (float*)(ws + 41943040);       // NN*NH f32 (51.2 MB)
    float* h2    = (float*)(ws + 94371840);       // NN*NC f32 (8 MB)
    unsigned short* Wth = (unsigned short*)(ws + 104857600);          // 128 KB
    unsigned short* Wtl = (unsigned short*)(ws + 104857600 + 131072); // 128 KB

    dim3 b(256);
    k_init      <<<(NN + 255) / 256, b, 0, stream>>>(cnt);
    k_count     <<<(NE + 255) / 256, b, 0, stream>>>(ei, cnt);
    k_scan_a    <<<SCAN_NBLK, b, 0, stream>>>(cnt, part);
    k_scan_b    <<<1, 64, 0, stream>>>(part);
    k_scan_c    <<<SCAN_NBLK, b, 0, stream>>>(cnt, part, ptr, cursor);
    k_scatter   <<<(NE + 255) / 256, b, 0, stream>>>(ei, ew, cursor, csre);
    k_deg_csr   <<<(NN + 255) / 256, b, 0, stream>>>(ptr, csre, dinv);
    k_coeff_csr <<<(NN + 255) / 256, b, 0, stream>>>(ptr, dinv, csre);

    k_splitW    <<<256, b, 0, stream>>>(W1, Wth, Wtl);
    k_gemm1     <<<(NN + 63) / 64, b, 0, stream>>>(x, Wth, Wtl, hb);
    k_agg1_gather<<<(int)(((long)NN * 32 + 255) / 256), b, 0, stream>>>(hb, dinv, ptr, csre, b1, hagg);
    k_gemm2     <<<(NN + 127) / 128, b, 0, stream>>>(hagg, W2, h2);
    k_agg2_fused<<<(NN + 255) / 256, b, 0, stream>>>(h2, dinv, ptr, csre, b2, out);
}